// Round 1
// 2382.918 us; speedup vs baseline: 4.9738x; 4.9738x over previous
//
#include <hip/hip_runtime.h>
#include <stdint.h>
#include <math.h>

// ============================================================================
// StackedEncoderModel, round 5: replace the 88-TF fp32 VALU GEMM with a
// split-precision bf16 MFMA GEMM (A,B -> bf16 hi/lo; C = Ah*Bh + Al*Bh + Ah*Bl,
// fp32 MFMA accumulation; per-product error ~2^-17, negligible vs the 0.0156
// scan-order absmax). Operands are pre-tiled into MFMA fragment order by
// convert kernels so global_load_lds's linear destination yields a
// bank-conflict-free LDS layout. m97 structure: 128x128 tile, BK=32, 4 waves,
// 2 barriers / K-step, global_load_lds dwordx4 staging.
// ============================================================================

#define LAYERS 4
#define TT     4096
#define DMODEL 2048
#define DHID   1024
#define NCHUNK 64
#define CLEN   64   // TT / NCHUNK
#define KTILES 64   // 2048 / 32

typedef unsigned short ushort_t;
typedef __attribute__((ext_vector_type(8))) short  short8;
typedef __attribute__((ext_vector_type(4))) float  f32x4;

__device__ __forceinline__ ushort_t bf16_rne(float v) {
  unsigned b = __float_as_uint(v);
  return (ushort_t)((b + 0x7FFFu + ((b >> 16) & 1u)) >> 16);
}

// ----------------------------------------------------------------------------
// convert_hilo: fp32 source (with gemm_v's B0/B1/NS/KS split addressing) ->
// bf16 hi/lo in tiled layout: tile (mb,kb) is 128 rows x 32 k, stored as
// [kg 0..3][m 0..127][j 0..7] contiguous 16B chunks (8KB per tile).
// Grid: (Mrows/128, 64). Block 256.
// ----------------------------------------------------------------------------
__global__ __launch_bounds__(256)
void convert_hilo(const float* __restrict__ B0, const float* __restrict__ B1,
                  int ldb, int NS, int KS,
                  ushort_t* __restrict__ Hi, ushort_t* __restrict__ Lo)
{
  __shared__ float tile[128][33];
  const int mb  = blockIdx.x;
  const int kb  = blockIdx.y;
  const int tid = threadIdx.x;
  const int r0  = tid >> 3;          // 0..31
  const int c0  = (tid & 7) * 4;     // 0..28
#pragma unroll
  for (int rep = 0; rep < 4; ++rep) {
    const int rr = rep * 32 + r0;
    const int n  = mb * 128 + rr;
    const int k  = kb * 32 + c0;
    const float* bp; long idx;
    if (n >= NS)      { bp = B1; idx = (long)(n - NS) * ldb + k; }
    else if (k >= KS) { bp = B1; idx = (long)n * ldb + (k - KS); }
    else              { bp = B0; idx = (long)n * ldb + k; }
#pragma unroll
    for (int u = 0; u < 4; ++u) tile[rr][c0 + u] = bp[idx + u];
  }
  __syncthreads();
#pragma unroll
  for (int rep = 0; rep < 2; ++rep) {
    const int id2 = rep * 256 + tid;
    const int kg  = id2 >> 7;        // 0..3
    const int m   = id2 & 127;
    unsigned hw[4], lw[4];
#pragma unroll
    for (int p = 0; p < 4; ++p) {
      unsigned hpair = 0, lpair = 0;
#pragma unroll
      for (int e = 0; e < 2; ++e) {
        const float v = tile[m][kg * 8 + p * 2 + e];
        const ushort_t h = bf16_rne(v);
        const float hf = __uint_as_float(((unsigned)h) << 16);
        const ushort_t l = bf16_rne(v - hf);
        hpair |= ((unsigned)h) << (16 * e);
        lpair |= ((unsigned)l) << (16 * e);
      }
      hw[p] = hpair; lw[p] = lpair;
    }
    const long off = ((long)mb * KTILES + kb) * 4096 + (kg * 128 + m) * 8;
    *(uint4*)&Hi[off] = make_uint4(hw[0], hw[1], hw[2], hw[3]);
    *(uint4*)&Lo[off] = make_uint4(lw[0], lw[1], lw[2], lw[3]);
  }
}

// ----------------------------------------------------------------------------
// MFMA split-precision GEMM: C[4096][2048] fp32 = A @ B^T (+bias),
// A,B given as tiled bf16 hi/lo (layout above). Grid (32,16), block 256.
// ----------------------------------------------------------------------------
#define GLDS(gp, lp) __builtin_amdgcn_global_load_lds( \
    (__attribute__((address_space(1))) void*)(void*)(gp), \
    (__attribute__((address_space(3))) void*)(lp), 16, 0, 0)

__global__ __launch_bounds__(256)
void gemm_mfma(const ushort_t* __restrict__ Ahi, const ushort_t* __restrict__ Alo,
               const ushort_t* __restrict__ Bhi, const ushort_t* __restrict__ Blo,
               float* __restrict__ C, const float* __restrict__ bias)
{
  __shared__ ushort_t As_h[4096], As_l[4096], Bs_h[4096], Bs_l[4096];
  const int tid  = threadIdx.x;
  const int lane = tid & 63;
  const int wid  = tid >> 6;
  const int wm   = wid >> 1;       // wave row-block (64 rows)
  const int wn   = wid & 1;        // wave col-block (64 cols)
  const int mb   = blockIdx.x;
  const int nb   = blockIdx.y;

  f32x4 acc[4][4];
#pragma unroll
  for (int i = 0; i < 4; ++i)
#pragma unroll
    for (int j = 0; j < 4; ++j) acc[i][j] = (f32x4){0.f, 0.f, 0.f, 0.f};

  const ushort_t* ga_h = Ahi + (long)mb * KTILES * 4096 + tid * 8;
  const ushort_t* ga_l = Alo + (long)mb * KTILES * 4096 + tid * 8;
  const ushort_t* gb_h = Bhi + (long)nb * KTILES * 4096 + tid * 8;
  const ushort_t* gb_l = Blo + (long)nb * KTILES * 4096 + tid * 8;

  // fragment base: row (lane&15) of the wave's 16-row block, k-group lane>>4
  const int albase = ((lane >> 4) * 128 + wm * 64 + (lane & 15)) * 8;
  const int blbase = ((lane >> 4) * 128 + wn * 64 + (lane & 15)) * 8;

  for (int kt = 0; kt < KTILES; ++kt) {
    GLDS(ga_h,        &As_h[tid * 8]);
    GLDS(ga_h + 2048, &As_h[2048 + tid * 8]);
    GLDS(ga_l,        &As_l[tid * 8]);
    GLDS(ga_l + 2048, &As_l[2048 + tid * 8]);
    GLDS(gb_h,        &Bs_h[tid * 8]);
    GLDS(gb_h + 2048, &Bs_h[2048 + tid * 8]);
    GLDS(gb_l,        &Bs_l[tid * 8]);
    GLDS(gb_l + 2048, &Bs_l[2048 + tid * 8]);
    ga_h += 4096; ga_l += 4096; gb_h += 4096; gb_l += 4096;
    __syncthreads();   // compiler drains vmcnt before barrier -> LDS ready

    short8 a_h[4], a_l[4], b_h[4], b_l[4];
#pragma unroll
    for (int m = 0; m < 4; ++m) {
      a_h[m] = *(const short8*)&As_h[albase + m * 128];
      a_l[m] = *(const short8*)&As_l[albase + m * 128];
    }
#pragma unroll
    for (int n = 0; n < 4; ++n) {
      b_h[n] = *(const short8*)&Bs_h[blbase + n * 128];
      b_l[n] = *(const short8*)&Bs_l[blbase + n * 128];
    }
#pragma unroll
    for (int m = 0; m < 4; ++m)
#pragma unroll
      for (int n = 0; n < 4; ++n) {
        acc[m][n] = __builtin_amdgcn_mfma_f32_16x16x32_bf16(a_h[m], b_h[n], acc[m][n], 0, 0, 0);
        acc[m][n] = __builtin_amdgcn_mfma_f32_16x16x32_bf16(a_l[m], b_h[n], acc[m][n], 0, 0, 0);
        acc[m][n] = __builtin_amdgcn_mfma_f32_16x16x32_bf16(a_h[m], b_l[n], acc[m][n], 0, 0, 0);
      }
    __syncthreads();   // protect LDS before next iteration's staging
  }

  // C/D layout (HW-verified): col = lane&15, row = (lane>>4)*4 + reg
  const int cn = lane & 15;
  const int cr = (lane >> 4) * 4;
#pragma unroll
  for (int m = 0; m < 4; ++m) {
    const long row = (long)mb * 128 + wm * 64 + m * 16 + cr;
#pragma unroll
    for (int n = 0; n < 4; ++n) {
      const int col = nb * 128 + wn * 64 + n * 16 + cn;
      const float bv = bias ? bias[col] : 0.0f;
#pragma unroll
      for (int q = 0; q < 4; ++q)
        C[(row + q) * 2048 + col] = acc[m][n][q] + bv;
    }
  }
}

// ---------------------------------------------------------------------------
// BatchNorm (training-mode, biased var over T).
// ---------------------------------------------------------------------------
__global__ void bn_partial(const float* __restrict__ carry, float* __restrict__ stats)
{
  const int j  = blockIdx.x * 256 + threadIdx.x;
  const int r0 = blockIdx.y * 128;
  float s = 0.f, ss = 0.f;
  for (int r = 0; r < 128; ++r) {
    float v = carry[(long)(r0 + r) * DMODEL + j];
    s += v; ss += v * v;
  }
  atomicAdd(&stats[j], s);
  atomicAdd(&stats[DMODEL + j], ss);
}

__global__ void bn_apply(const float* __restrict__ carry, const float* __restrict__ stats,
                         const float* __restrict__ nw, const float* __restrict__ nb,
                         float* __restrict__ act)
{
  const long idx = (long)blockIdx.x * 256 + threadIdx.x;
  const int j = (int)(idx & (DMODEL - 1));
  const float mean = stats[j] * (1.0f / TT);
  const float var  = fmaxf(stats[DMODEL + j] * (1.0f / TT) - mean * mean, 0.0f);
  const float rstd = rsqrtf(var + 1e-5f);
  act[idx] = (carry[idx] - mean) * rstd * nw[j] + nb[j];
}

// ---------------------------------------------------------------------------
// LRU blocked scan. Bu layout: fp32 [T][2048], cols 0:1024 re, 1024:2048 im.
// ---------------------------------------------------------------------------
__device__ __forceinline__ void get_lam(const float* nu_log, const float* th_log,
                                        int h, float& lre, float& lim)
{
  const float mag = expf(-expf(nu_log[h]));
  const float th  = expf(th_log[h]);
  lre = mag * cosf(th);
  lim = mag * sinf(th);
}

__global__ void scan1(float* __restrict__ bu,
                      const float* __restrict__ nu_log, const float* __restrict__ th_log,
                      const float* __restrict__ gl_log)
{
  const int gid = blockIdx.x * 256 + threadIdx.x;
  const int c = gid >> 10, h = gid & 1023;
  float lre, lim; get_lam(nu_log, th_log, h, lre, lim);
  const float gamma = expf(gl_log[h]);
  float hr = 0.f, hi = 0.f;
  for (int i = 0; i < CLEN; ++i) {
    const long t = (long)c * CLEN + i;
    const float br_ = bu[t * 2048 + h] * gamma;
    const float bi_ = bu[t * 2048 + 1024 + h] * gamma;
    const float nr = lre * hr - lim * hi + br_;
    const float ni = lre * hi + lim * hr + bi_;
    hr = nr; hi = ni;
    bu[t * 2048 + h] = hr;
    bu[t * 2048 + 1024 + h] = hi;
  }
}

__global__ void scan2(const float* __restrict__ loc,
                      float* __restrict__ ccre, float* __restrict__ ccim,
                      const float* __restrict__ nu_log, const float* __restrict__ th_log)
{
  const int h = blockIdx.x * 256 + threadIdx.x;  // 0..1023
  float lre, lim; get_lam(nu_log, th_log, h, lre, lim);
  float ar = lre, ai = lim;                       // lam^64 via 6 squarings
  for (int s = 0; s < 6; ++s) { float nr = ar * ar - ai * ai, ni = 2.f * ar * ai; ar = nr; ai = ni; }
  float er = 0.f, ei = 0.f;
  for (int c = 0; c < NCHUNK; ++c) {
    ccre[c * DHID + h] = er; ccim[c * DHID + h] = ei;
    const long t = (long)c * CLEN + (CLEN - 1);
    const float nr = ar * er - ai * ei + loc[t * 2048 + h];
    const float ni = ar * ei + ai * er + loc[t * 2048 + 1024 + h];
    er = nr; ei = ni;
  }
}

// scan3 now runs IN PLACE on loc, leaving [h_re | -h_im] for the C-projection.
__global__ void scan3(float* __restrict__ loc,
                      const float* __restrict__ ccre, const float* __restrict__ ccim,
                      const float* __restrict__ nu_log, const float* __restrict__ th_log)
{
  const int gid = blockIdx.x * 256 + threadIdx.x;
  const int c = gid >> 10, h = gid & 1023;
  float lre, lim; get_lam(nu_log, th_log, h, lre, lim);
  const float cr_ = ccre[c * DHID + h], ci_ = ccim[c * DHID + h];
  float pr = lre, pi = lim;   // lam^(i+1)
  for (int i = 0; i < CLEN; ++i) {
    const long t = (long)c * CLEN + i;
    const float hre = loc[t * 2048 + h]        + pr * cr_ - pi * ci_;
    const float him = loc[t * 2048 + 1024 + h] + pr * ci_ + pi * cr_;
    const float npr = pr * lre - pi * lim, npi = pr * lim + pi * lre;
    pr = npr; pi = npi;
    loc[t * 2048 + h]        = hre;
    loc[t * 2048 + 1024 + h] = -him;
  }
}

// ---------------------------------------------------------------------------
// Elementwise epilogues (fp32)
// ---------------------------------------------------------------------------
__global__ void e1_kernel(const float* __restrict__ y,
                          float* __restrict__ act,
                          const float* __restrict__ d)
{
  const long idx = (long)blockIdx.x * 256 + threadIdx.x;
  const int j = (int)(idx & (DMODEL - 1));
  const float v = y[idx] + act[idx] * d[j];
  act[idx] = 0.5f * v * (1.0f + erff(v * 0.70710678118654752440f));
}

__global__ void e2_kernel(float* __restrict__ carry,
                          const float* __restrict__ t1, const float* __restrict__ t2,
                          const float* __restrict__ b1, const float* __restrict__ b2)
{
  const long idx = (long)blockIdx.x * 256 + threadIdx.x;
  const int j = (int)(idx & (DMODEL - 1));
  const float a = t1[idx] + b1[j];
  const float s = t2[idx] + b2[j];
  carry[idx] += a * (1.0f / (1.0f + expf(-s)));
}

__global__ void finalize(const float* __restrict__ carry, float* __restrict__ out)
{
  const long idx = (long)blockIdx.x * 256 + threadIdx.x;
  const float v = carry[idx];
  out[idx] = (v == v && fabsf(v) < 3.0e38f) ? v : 300000.0f;
}

__global__ void diagfill(float* __restrict__ out, float val)
{
  const long idx = (long)blockIdx.x * 256 + threadIdx.x;
  out[idx] = (idx == 0) ? val : 0.0f;
}

// ---------------------------------------------------------------------------
extern "C" void kernel_launch(void* const* d_in, const int* in_sizes, int n_in,
                              void* d_out, int out_size, void* d_ws, size_t ws_size,
                              hipStream_t stream)
{
  (void)out_size;
  const int EW = (TT * DMODEL) / 256;
  float* out = (float*)d_out;

  if (n_in != 17 || in_sizes[0] != TT * DMODEL) {
    diagfill<<<EW, 256, 0, stream>>>(out, (float)(1 << 18));
    return;
  }
  // need 151,535,616 B of workspace (proven available: previous guard 168.5MB passed)
  if (ws_size < 151600000ull) {
    diagfill<<<EW, 256, 0, stream>>>(out, (float)(1 << 12));
    return;
  }

  const float* x     = (const float*)d_in[0];
  const float* enc_w = (const float*)d_in[1];
  const float* enc_b = (const float*)d_in[2];
  const float* nu    = (const float*)d_in[3];
  const float* th    = (const float*)d_in[4];
  const float* gl    = (const float*)d_in[5];
  const float* Bre   = (const float*)d_in[6];
  const float* Bim   = (const float*)d_in[7];
  const float* Cre   = (const float*)d_in[8];
  const float* Cim   = (const float*)d_in[9];
  const float* Dd    = (const float*)d_in[10];
  const float* nw    = (const float*)d_in[11];
  const float* nb    = (const float*)d_in[12];
  const float* w1    = (const float*)d_in[13];
  const float* b1    = (const float*)d_in[14];
  const float* w2    = (const float*)d_in[15];
  const float* b2    = (const float*)d_in[16];

  char* ws = (char*)d_ws;
  float*    carry = (float*)(ws);                 // [T][DM] residual stream
  float*    act   = (float*)(ws + 33554432);      // xn -> g -> t2
  float*    buf1  = (float*)(ws + 67108864);      // Bu -> ah -> y -> t1
  ushort_t* Ahi   = (ushort_t*)(ws + 100663296);  // tiled bf16 hi of A operand
  ushort_t* Alo   = (ushort_t*)(ws + 117440512);
  ushort_t* Bhi   = (ushort_t*)(ws + 134217728);  // tiled bf16 hi of B operand
  ushort_t* Blo   = (ushort_t*)(ws + 142606336);
  float*    ccre  = (float*)(ws + 150994944);
  float*    ccim  = (float*)(ws + 151257088);
  float*    stats = (float*)(ws + 151519232);

  const dim3 gcA(32, 64);   // 4096-row operand, 64 k-tiles
  const dim3 gcW(16, 64);   // 2048-row operand
  const dim3 gg(32, 16);    // GEMM: 32 m-blocks x 16 n-blocks
  const int BIG = 1 << 30;

  // encoder: carry = x @ enc_w^T + enc_b
  convert_hilo<<<gcA, 256, 0, stream>>>(x, x, 2048, BIG, BIG, Ahi, Alo);
  convert_hilo<<<gcW, 256, 0, stream>>>(enc_w, enc_w, 2048, BIG, BIG, Bhi, Blo);
  gemm_mfma<<<gg, 256, 0, stream>>>(Ahi, Alo, Bhi, Blo, carry, enc_b);

  for (int l = 0; l < LAYERS; ++l) {
    const float* Brl = Bre + (size_t)l * DHID * DMODEL;
    const float* Bil = Bim + (size_t)l * DHID * DMODEL;
    const float* Crl = Cre + (size_t)l * DMODEL * DHID;
    const float* Cil = Cim + (size_t)l * DMODEL * DHID;
    const float* w1l = w1 + (size_t)l * DMODEL * DMODEL;
    const float* w2l = w2 + (size_t)l * DMODEL * DMODEL;

    // BatchNorm -> act (xn)
    hipMemsetAsync(stats, 0, 2 * DMODEL * sizeof(float), stream);
    bn_partial<<<dim3(DMODEL / 256, TT / 128), 256, 0, stream>>>(carry, stats);
    bn_apply<<<EW, 256, 0, stream>>>(carry, stats, nw + l * DMODEL, nb + l * DMODEL, act);

    // Bu = xn @ [B_re; B_im]^T  (row-split at 1024) -> buf1 [re|im]
    convert_hilo<<<gcA, 256, 0, stream>>>(act, act, 2048, BIG, BIG, Ahi, Alo);
    convert_hilo<<<gcW, 256, 0, stream>>>(Brl, Bil, 2048, 1024, BIG, Bhi, Blo);
    gemm_mfma<<<gg, 256, 0, stream>>>(Ahi, Alo, Bhi, Blo, buf1, nullptr);

    // diagonal complex scan over T (scan3 in place: buf1 := [h_re | -h_im])
    scan1<<<256, 256, 0, stream>>>(buf1, nu + l * DHID, th + l * DHID, gl + l * DHID);
    scan2<<<4, 256, 0, stream>>>(buf1, ccre, ccim, nu + l * DHID, th + l * DHID);
    scan3<<<256, 256, 0, stream>>>(buf1, ccre, ccim, nu + l * DHID, th + l * DHID);

    // y = [h_re|-h_im] @ [C_re|C_im]^T (col-split at 1024, ldb=1024) -> buf1
    convert_hilo<<<gcA, 256, 0, stream>>>(buf1, buf1, 2048, BIG, BIG, Ahi, Alo);
    convert_hilo<<<gcW, 256, 0, stream>>>(Crl, Cil, 1024, BIG, 1024, Bhi, Blo);
    gemm_mfma<<<gg, 256, 0, stream>>>(Ahi, Alo, Bhi, Blo, buf1, nullptr);

    // act := gelu(y + xn*d)   (in place on act)
    e1_kernel<<<EW, 256, 0, stream>>>(buf1, act, Dd + l * DMODEL);

    // t1 = g @ w1^T -> buf1 ; t2 = g @ w2^T -> act (g already converted)
    convert_hilo<<<gcA, 256, 0, stream>>>(act, act, 2048, BIG, BIG, Ahi, Alo);
    convert_hilo<<<gcW, 256, 0, stream>>>(w1l, w1l, 2048, BIG, BIG, Bhi, Blo);
    gemm_mfma<<<gg, 256, 0, stream>>>(Ahi, Alo, Bhi, Blo, buf1, nullptr);
    convert_hilo<<<gcW, 256, 0, stream>>>(w2l, w2l, 2048, BIG, BIG, Bhi, Blo);
    gemm_mfma<<<gg, 256, 0, stream>>>(Ahi, Alo, Bhi, Blo, act, nullptr);

    // carry += (t1+b1)*sigmoid(t2+b2)
    e2_kernel<<<EW, 256, 0, stream>>>(carry, buf1, act, b1 + l * DMODEL, b2 + l * DMODEL);
  }

  finalize<<<EW, 256, 0, stream>>>(carry, out);
}

// Round 2
// 2321.772 us; speedup vs baseline: 5.1048x; 1.0263x over previous
//
#include <hip/hip_runtime.h>
#include <stdint.h>
#include <math.h>

// ============================================================================
// StackedEncoderModel, round 6.
//  - GEMM: split-precision bf16 MFMA (C = Ah*Bh + Al*Bh + Ah*Bl), now with
//    T3 "minimal 2-phase" double-buffered LDS pipeline: stage tile t+1 while
//    computing tile t, ONE vmcnt(0)+barrier per K-step (was stage/barrier/
//    compute/barrier), plus T5 setprio around the MFMA cluster.
//  - Fusions: bn_convert = BN-apply + A-operand hi/lo tiling;
//             e1_convert = gelu(y + xn*d) + A-operand hi/lo tiling
//    (removes 8 full 32MB elementwise/convert passes per call).
// Tiled operand layout (unchanged): tile (mb,kb) = 128 rows x 32 k, stored
// [kg 0..3][m 0..127][j 0..7] bf16, 8KB per tile; kg = (k within tile)/8.
// ============================================================================

#define LAYERS 4
#define TT     4096
#define DMODEL 2048
#define DHID   1024
#define NCHUNK 64
#define CLEN   64   // TT / NCHUNK
#define KTILES 64   // 2048 / 32

typedef unsigned short ushort_t;
typedef __attribute__((ext_vector_type(8))) short  short8;
typedef __attribute__((ext_vector_type(4))) float  f32x4;

__device__ __forceinline__ ushort_t bf16_rne(float v) {
  unsigned b = __float_as_uint(v);
  return (ushort_t)((b + 0x7FFFu + ((b >> 16) & 1u)) >> 16);
}

// ----------------------------------------------------------------------------
// convert_hilo: fp32 source (with B0/B1/NS/KS split addressing) -> bf16 hi/lo
// in tiled layout. Grid: (Mrows/128, 64). Block 256.
// ----------------------------------------------------------------------------
__global__ __launch_bounds__(256)
void convert_hilo(const float* __restrict__ B0, const float* __restrict__ B1,
                  int ldb, int NS, int KS,
                  ushort_t* __restrict__ Hi, ushort_t* __restrict__ Lo)
{
  __shared__ float tile[128][33];
  const int mb  = blockIdx.x;
  const int kb  = blockIdx.y;
  const int tid = threadIdx.x;
  const int r0  = tid >> 3;          // 0..31
  const int c0  = (tid & 7) * 4;     // 0..28
#pragma unroll
  for (int rep = 0; rep < 4; ++rep) {
    const int rr = rep * 32 + r0;
    const int n  = mb * 128 + rr;
    const int k  = kb * 32 + c0;
    const float* bp; long idx;
    if (n >= NS)      { bp = B1; idx = (long)(n - NS) * ldb + k; }
    else if (k >= KS) { bp = B1; idx = (long)n * ldb + (k - KS); }
    else              { bp = B0; idx = (long)n * ldb + k; }
#pragma unroll
    for (int u = 0; u < 4; ++u) tile[rr][c0 + u] = bp[idx + u];
  }
  __syncthreads();
#pragma unroll
  for (int rep = 0; rep < 2; ++rep) {
    const int id2 = rep * 256 + tid;
    const int kg  = id2 >> 7;        // 0..3
    const int m   = id2 & 127;
    unsigned hw[4], lw[4];
#pragma unroll
    for (int p = 0; p < 4; ++p) {
      unsigned hpair = 0, lpair = 0;
#pragma unroll
      for (int e = 0; e < 2; ++e) {
        const float v = tile[m][kg * 8 + p * 2 + e];
        const ushort_t h = bf16_rne(v);
        const float hf = __uint_as_float(((unsigned)h) << 16);
        const ushort_t l = bf16_rne(v - hf);
        hpair |= ((unsigned)h) << (16 * e);
        lpair |= ((unsigned)l) << (16 * e);
      }
      hw[p] = hpair; lw[p] = lpair;
    }
    const long off = ((long)mb * KTILES + kb) * 4096 + (kg * 128 + m) * 8;
    *(uint4*)&Hi[off] = make_uint4(hw[0], hw[1], hw[2], hw[3]);
    *(uint4*)&Lo[off] = make_uint4(lw[0], lw[1], lw[2], lw[3]);
  }
}

// ----------------------------------------------------------------------------
// bn_convert: BN-apply fused with hi/lo tiling. Reads carry + stats; writes
// act (xn, fp32, row-major — needed by e1) AND tiled hi/lo. Grid (32,64).
// ----------------------------------------------------------------------------
__global__ __launch_bounds__(256)
void bn_convert(const float* __restrict__ carry, const float* __restrict__ stats,
                const float* __restrict__ nw, const float* __restrict__ nb,
                float* __restrict__ act,
                ushort_t* __restrict__ Hi, ushort_t* __restrict__ Lo)
{
  __shared__ float tile[128][33];
  const int mb  = blockIdx.x;
  const int kb  = blockIdx.y;
  const int tid = threadIdx.x;
  const int r0  = tid >> 3;
  const int c0  = (tid & 7) * 4;
  // per-thread column constants (4 columns, fixed across reps)
  float mean[4], rstd[4], w_[4], b_[4];
#pragma unroll
  for (int u = 0; u < 4; ++u) {
    const int j = kb * 32 + c0 + u;
    const float mu = stats[j] * (1.0f / TT);
    const float va = fmaxf(stats[DMODEL + j] * (1.0f / TT) - mu * mu, 0.0f);
    mean[u] = mu; rstd[u] = rsqrtf(va + 1e-5f);
    w_[u] = nw[j]; b_[u] = nb[j];
  }
#pragma unroll
  for (int rep = 0; rep < 4; ++rep) {
    const int rr  = rep * 32 + r0;
    const long base = (long)(mb * 128 + rr) * 2048 + kb * 32 + c0;
#pragma unroll
    for (int u = 0; u < 4; ++u) {
      const float v = (carry[base + u] - mean[u]) * rstd[u] * w_[u] + b_[u];
      tile[rr][c0 + u] = v;
      act[base + u] = v;
    }
  }
  __syncthreads();
#pragma unroll
  for (int rep = 0; rep < 2; ++rep) {
    const int id2 = rep * 256 + tid;
    const int kg  = id2 >> 7;
    const int m   = id2 & 127;
    unsigned hw[4], lw[4];
#pragma unroll
    for (int p = 0; p < 4; ++p) {
      unsigned hpair = 0, lpair = 0;
#pragma unroll
      for (int e = 0; e < 2; ++e) {
        const float v = tile[m][kg * 8 + p * 2 + e];
        const ushort_t h = bf16_rne(v);
        const float hf = __uint_as_float(((unsigned)h) << 16);
        const ushort_t l = bf16_rne(v - hf);
        hpair |= ((unsigned)h) << (16 * e);
        lpair |= ((unsigned)l) << (16 * e);
      }
      hw[p] = hpair; lw[p] = lpair;
    }
    const long off = ((long)mb * KTILES + kb) * 4096 + (kg * 128 + m) * 8;
    *(uint4*)&Hi[off] = make_uint4(hw[0], hw[1], hw[2], hw[3]);
    *(uint4*)&Lo[off] = make_uint4(lw[0], lw[1], lw[2], lw[3]);
  }
}

// ----------------------------------------------------------------------------
// e1_convert: g = gelu(y + xn*d), emitted ONLY as tiled hi/lo (g fp32 is
// never consumed downstream). Grid (32,64).
// ----------------------------------------------------------------------------
__global__ __launch_bounds__(256)
void e1_convert(const float* __restrict__ y, const float* __restrict__ xn,
                const float* __restrict__ d,
                ushort_t* __restrict__ Hi, ushort_t* __restrict__ Lo)
{
  __shared__ float tile[128][33];
  const int mb  = blockIdx.x;
  const int kb  = blockIdx.y;
  const int tid = threadIdx.x;
  const int r0  = tid >> 3;
  const int c0  = (tid & 7) * 4;
  float dv[4];
#pragma unroll
  for (int u = 0; u < 4; ++u) dv[u] = d[kb * 32 + c0 + u];
#pragma unroll
  for (int rep = 0; rep < 4; ++rep) {
    const int rr  = rep * 32 + r0;
    const long base = (long)(mb * 128 + rr) * 2048 + kb * 32 + c0;
#pragma unroll
    for (int u = 0; u < 4; ++u) {
      const float v = y[base + u] + xn[base + u] * dv[u];
      tile[rr][c0 + u] = 0.5f * v * (1.0f + erff(v * 0.70710678118654752440f));
    }
  }
  __syncthreads();
#pragma unroll
  for (int rep = 0; rep < 2; ++rep) {
    const int id2 = rep * 256 + tid;
    const int kg  = id2 >> 7;
    const int m   = id2 & 127;
    unsigned hw[4], lw[4];
#pragma unroll
    for (int p = 0; p < 4; ++p) {
      unsigned hpair = 0, lpair = 0;
#pragma unroll
      for (int e = 0; e < 2; ++e) {
        const float v = tile[m][kg * 8 + p * 2 + e];
        const ushort_t h = bf16_rne(v);
        const float hf = __uint_as_float(((unsigned)h) << 16);
        const ushort_t l = bf16_rne(v - hf);
        hpair |= ((unsigned)h) << (16 * e);
        lpair |= ((unsigned)l) << (16 * e);
      }
      hw[p] = hpair; lw[p] = lpair;
    }
    const long off = ((long)mb * KTILES + kb) * 4096 + (kg * 128 + m) * 8;
    *(uint4*)&Hi[off] = make_uint4(hw[0], hw[1], hw[2], hw[3]);
    *(uint4*)&Lo[off] = make_uint4(lw[0], lw[1], lw[2], lw[3]);
  }
}

// ----------------------------------------------------------------------------
// MFMA split-precision GEMM, 2-phase double-buffered. Grid (32,16), block 256.
// ----------------------------------------------------------------------------
#define GLDS(gp, lp) __builtin_amdgcn_global_load_lds( \
    (__attribute__((address_space(1))) void*)(void*)(gp), \
    (__attribute__((address_space(3))) void*)(lp), 16, 0, 0)

__global__ __launch_bounds__(256)
void gemm_mfma(const ushort_t* __restrict__ Ahi, const ushort_t* __restrict__ Alo,
               const ushort_t* __restrict__ Bhi, const ushort_t* __restrict__ Blo,
               float* __restrict__ C, const float* __restrict__ bias)
{
  __shared__ ushort_t As_h[2][4096], As_l[2][4096], Bs_h[2][4096], Bs_l[2][4096];
  const int tid  = threadIdx.x;
  const int lane = tid & 63;
  const int wid  = tid >> 6;
  const int wm   = wid >> 1;
  const int wn   = wid & 1;
  const int mb   = blockIdx.x;
  const int nb   = blockIdx.y;

  f32x4 acc[4][4];
#pragma unroll
  for (int i = 0; i < 4; ++i)
#pragma unroll
    for (int j = 0; j < 4; ++j) acc[i][j] = (f32x4){0.f, 0.f, 0.f, 0.f};

  const ushort_t* ga_h = Ahi + (long)mb * KTILES * 4096 + tid * 8;
  const ushort_t* ga_l = Alo + (long)mb * KTILES * 4096 + tid * 8;
  const ushort_t* gb_h = Bhi + (long)nb * KTILES * 4096 + tid * 8;
  const ushort_t* gb_l = Blo + (long)nb * KTILES * 4096 + tid * 8;

  const int albase = ((lane >> 4) * 128 + wm * 64 + (lane & 15)) * 8;
  const int blbase = ((lane >> 4) * 128 + wn * 64 + (lane & 15)) * 8;

#define STAGE(p) \
  GLDS(ga_h,        &As_h[p][tid * 8]); \
  GLDS(ga_h + 2048, &As_h[p][2048 + tid * 8]); \
  GLDS(ga_l,        &As_l[p][tid * 8]); \
  GLDS(ga_l + 2048, &As_l[p][2048 + tid * 8]); \
  GLDS(gb_h,        &Bs_h[p][tid * 8]); \
  GLDS(gb_h + 2048, &Bs_h[p][2048 + tid * 8]); \
  GLDS(gb_l,        &Bs_l[p][tid * 8]); \
  GLDS(gb_l + 2048, &Bs_l[p][2048 + tid * 8]); \
  ga_h += 4096; ga_l += 4096; gb_h += 4096; gb_l += 4096;

#define COMPUTE(p) { \
  short8 a_h[4], a_l[4], b_h[4], b_l[4]; \
  _Pragma("unroll") \
  for (int m = 0; m < 4; ++m) { \
    a_h[m] = *(const short8*)&As_h[p][albase + m * 128]; \
    a_l[m] = *(const short8*)&As_l[p][albase + m * 128]; \
  } \
  _Pragma("unroll") \
  for (int n = 0; n < 4; ++n) { \
    b_h[n] = *(const short8*)&Bs_h[p][blbase + n * 128]; \
    b_l[n] = *(const short8*)&Bs_l[p][blbase + n * 128]; \
  } \
  __builtin_amdgcn_s_setprio(1); \
  _Pragma("unroll") \
  for (int m = 0; m < 4; ++m) \
    _Pragma("unroll") \
    for (int n = 0; n < 4; ++n) { \
      acc[m][n] = __builtin_amdgcn_mfma_f32_16x16x32_bf16(a_h[m], b_h[n], acc[m][n], 0, 0, 0); \
      acc[m][n] = __builtin_amdgcn_mfma_f32_16x16x32_bf16(a_l[m], b_h[n], acc[m][n], 0, 0, 0); \
      acc[m][n] = __builtin_amdgcn_mfma_f32_16x16x32_bf16(a_h[m], b_l[n], acc[m][n], 0, 0, 0); \
    } \
  __builtin_amdgcn_s_setprio(0); }

  STAGE(0)
  __syncthreads();                 // vmcnt(0) drain + barrier: buf0 ready
  for (int kt = 0; kt < 62; kt += 2) {
    STAGE(1)                       // issue next tile's loads (fly during compute)
    COMPUTE(0)
    __syncthreads();               // drains vmcnt(0): buf1 ready; buf0 free
    STAGE(0)
    COMPUTE(1)
    __syncthreads();
  }
  STAGE(1)
  COMPUTE(0)
  __syncthreads();
  COMPUTE(1)
#undef STAGE
#undef COMPUTE

  // C/D layout (HW-verified): col = lane&15, row = (lane>>4)*4 + reg
  const int cn = lane & 15;
  const int cr = (lane >> 4) * 4;
#pragma unroll
  for (int m = 0; m < 4; ++m) {
    const long row = (long)mb * 128 + wm * 64 + m * 16 + cr;
#pragma unroll
    for (int n = 0; n < 4; ++n) {
      const int col = nb * 128 + wn * 64 + n * 16 + cn;
      const float bv = bias ? bias[col] : 0.0f;
#pragma unroll
      for (int q = 0; q < 4; ++q)
        C[(row + q) * 2048 + col] = acc[m][n][q] + bv;
    }
  }
}

// ---------------------------------------------------------------------------
// BatchNorm partial sums.
// ---------------------------------------------------------------------------
__global__ void bn_partial(const float* __restrict__ carry, float* __restrict__ stats)
{
  const int j  = blockIdx.x * 256 + threadIdx.x;
  const int r0 = blockIdx.y * 128;
  float s = 0.f, ss = 0.f;
  for (int r = 0; r < 128; ++r) {
    float v = carry[(long)(r0 + r) * DMODEL + j];
    s += v; ss += v * v;
  }
  atomicAdd(&stats[j], s);
  atomicAdd(&stats[DMODEL + j], ss);
}

// ---------------------------------------------------------------------------
// LRU blocked scan. Bu layout: fp32 [T][2048], cols 0:1024 re, 1024:2048 im.
// ---------------------------------------------------------------------------
__device__ __forceinline__ void get_lam(const float* nu_log, const float* th_log,
                                        int h, float& lre, float& lim)
{
  const float mag = expf(-expf(nu_log[h]));
  const float th  = expf(th_log[h]);
  lre = mag * cosf(th);
  lim = mag * sinf(th);
}

__global__ void scan1(float* __restrict__ bu,
                      const float* __restrict__ nu_log, const float* __restrict__ th_log,
                      const float* __restrict__ gl_log)
{
  const int gid = blockIdx.x * 256 + threadIdx.x;
  const int c = gid >> 10, h = gid & 1023;
  float lre, lim; get_lam(nu_log, th_log, h, lre, lim);
  const float gamma = expf(gl_log[h]);
  float hr = 0.f, hi = 0.f;
  for (int i = 0; i < CLEN; ++i) {
    const long t = (long)c * CLEN + i;
    const float br_ = bu[t * 2048 + h] * gamma;
    const float bi_ = bu[t * 2048 + 1024 + h] * gamma;
    const float nr = lre * hr - lim * hi + br_;
    const float ni = lre * hi + lim * hr + bi_;
    hr = nr; hi = ni;
    bu[t * 2048 + h] = hr;
    bu[t * 2048 + 1024 + h] = hi;
  }
}

__global__ void scan2(const float* __restrict__ loc,
                      float* __restrict__ ccre, float* __restrict__ ccim,
                      const float* __restrict__ nu_log, const float* __restrict__ th_log)
{
  const int h = blockIdx.x * 256 + threadIdx.x;  // 0..1023
  float lre, lim; get_lam(nu_log, th_log, h, lre, lim);
  float ar = lre, ai = lim;                       // lam^64 via 6 squarings
  for (int s = 0; s < 6; ++s) { float nr = ar * ar - ai * ai, ni = 2.f * ar * ai; ar = nr; ai = ni; }
  float er = 0.f, ei = 0.f;
  for (int c = 0; c < NCHUNK; ++c) {
    ccre[c * DHID + h] = er; ccim[c * DHID + h] = ei;
    const long t = (long)c * CLEN + (CLEN - 1);
    const float nr = ar * er - ai * ei + loc[t * 2048 + h];
    const float ni = ar * ei + ai * er + loc[t * 2048 + 1024 + h];
    er = nr; ei = ni;
  }
}

// scan3 runs IN PLACE on loc, leaving [h_re | -h_im] for the C-projection.
__global__ void scan3(float* __restrict__ loc,
                      const float* __restrict__ ccre, const float* __restrict__ ccim,
                      const float* __restrict__ nu_log, const float* __restrict__ th_log)
{
  const int gid = blockIdx.x * 256 + threadIdx.x;
  const int c = gid >> 10, h = gid & 1023;
  float lre, lim; get_lam(nu_log, th_log, h, lre, lim);
  const float cr_ = ccre[c * DHID + h], ci_ = ccim[c * DHID + h];
  float pr = lre, pi = lim;   // lam^(i+1)
  for (int i = 0; i < CLEN; ++i) {
    const long t = (long)c * CLEN + i;
    const float hre = loc[t * 2048 + h]        + pr * cr_ - pi * ci_;
    const float him = loc[t * 2048 + 1024 + h] + pr * ci_ + pi * cr_;
    const float npr = pr * lre - pi * lim, npi = pr * lim + pi * lre;
    pr = npr; pi = npi;
    loc[t * 2048 + h]        = hre;
    loc[t * 2048 + 1024 + h] = -him;
  }
}

// ---------------------------------------------------------------------------
// e2 epilogue + finalize
// ---------------------------------------------------------------------------
__global__ void e2_kernel(float* __restrict__ carry,
                          const float* __restrict__ t1, const float* __restrict__ t2,
                          const float* __restrict__ b1, const float* __restrict__ b2)
{
  const long idx = (long)blockIdx.x * 256 + threadIdx.x;
  const int j = (int)(idx & (DMODEL - 1));
  const float a = t1[idx] + b1[j];
  const float s = t2[idx] + b2[j];
  carry[idx] += a * (1.0f / (1.0f + expf(-s)));
}

__global__ void finalize(const float* __restrict__ carry, float* __restrict__ out)
{
  const long idx = (long)blockIdx.x * 256 + threadIdx.x;
  const float v = carry[idx];
  out[idx] = (v == v && fabsf(v) < 3.0e38f) ? v : 300000.0f;
}

__global__ void diagfill(float* __restrict__ out, float val)
{
  const long idx = (long)blockIdx.x * 256 + threadIdx.x;
  out[idx] = (idx == 0) ? val : 0.0f;
}

// ---------------------------------------------------------------------------
extern "C" void kernel_launch(void* const* d_in, const int* in_sizes, int n_in,
                              void* d_out, int out_size, void* d_ws, size_t ws_size,
                              hipStream_t stream)
{
  (void)out_size;
  const int EW = (TT * DMODEL) / 256;
  float* out = (float*)d_out;

  if (n_in != 17 || in_sizes[0] != TT * DMODEL) {
    diagfill<<<EW, 256, 0, stream>>>(out, (float)(1 << 18));
    return;
  }
  if (ws_size < 151600000ull) {
    diagfill<<<EW, 256, 0, stream>>>(out, (float)(1 << 12));
    return;
  }

  const float* x     = (const float*)d_in[0];
  const float* enc_w = (const float*)d_in[1];
  const float* enc_b = (const float*)d_in[2];
  const float* nu    = (const float*)d_in[3];
  const float* th    = (const float*)d_in[4];
  const float* gl    = (const float*)d_in[5];
  const float* Bre   = (const float*)d_in[6];
  const float* Bim   = (const float*)d_in[7];
  const float* Cre   = (const float*)d_in[8];
  const float* Cim   = (const float*)d_in[9];
  const float* Dd    = (const float*)d_in[10];
  const float* nw    = (const float*)d_in[11];
  const float* nb    = (const float*)d_in[12];
  const float* w1    = (const float*)d_in[13];
  const float* b1    = (const float*)d_in[14];
  const float* w2    = (const float*)d_in[15];
  const float* b2    = (const float*)d_in[16];

  char* ws = (char*)d_ws;
  float*    carry = (float*)(ws);                 // [T][DM] residual stream
  float*    act   = (float*)(ws + 33554432);      // xn -> t2
  float*    buf1  = (float*)(ws + 67108864);      // Bu -> ah -> y -> t1
  ushort_t* Ahi   = (ushort_t*)(ws + 100663296);  // tiled bf16 hi of A operand
  ushort_t* Alo   = (ushort_t*)(ws + 117440512);
  ushort_t* Bhi   = (ushort_t*)(ws + 134217728);  // tiled bf16 hi of B operand
  ushort_t* Blo   = (ushort_t*)(ws + 142606336);
  float*    ccre  = (float*)(ws + 150994944);
  float*    ccim  = (float*)(ws + 151257088);
  float*    stats = (float*)(ws + 151519232);

  const dim3 gcA(32, 64);   // 4096-row operand, 64 k-tiles
  const dim3 gcW(16, 64);   // 2048-row operand
  const dim3 gg(32, 16);    // GEMM: 32 m-blocks x 16 n-blocks
  const int BIG = 1 << 30;

  // encoder: carry = x @ enc_w^T + enc_b
  convert_hilo<<<gcA, 256, 0, stream>>>(x, x, 2048, BIG, BIG, Ahi, Alo);
  convert_hilo<<<gcW, 256, 0, stream>>>(enc_w, enc_w, 2048, BIG, BIG, Bhi, Blo);
  gemm_mfma<<<gg, 256, 0, stream>>>(Ahi, Alo, Bhi, Blo, carry, enc_b);

  for (int l = 0; l < LAYERS; ++l) {
    const float* Brl = Bre + (size_t)l * DHID * DMODEL;
    const float* Bil = Bim + (size_t)l * DHID * DMODEL;
    const float* Crl = Cre + (size_t)l * DMODEL * DHID;
    const float* Cil = Cim + (size_t)l * DMODEL * DHID;
    const float* w1l = w1 + (size_t)l * DMODEL * DMODEL;
    const float* w2l = w2 + (size_t)l * DMODEL * DMODEL;

    // BatchNorm stats, then fused BN-apply + A-convert (act=xn + Ahi/Alo)
    hipMemsetAsync(stats, 0, 2 * DMODEL * sizeof(float), stream);
    bn_partial<<<dim3(DMODEL / 256, TT / 128), 256, 0, stream>>>(carry, stats);
    bn_convert<<<gcA, 256, 0, stream>>>(carry, stats, nw + l * DMODEL, nb + l * DMODEL,
                                        act, Ahi, Alo);

    // Bu = xn @ [B_re; B_im]^T  (row-split at 1024) -> buf1 [re|im]
    convert_hilo<<<gcW, 256, 0, stream>>>(Brl, Bil, 2048, 1024, BIG, Bhi, Blo);
    gemm_mfma<<<gg, 256, 0, stream>>>(Ahi, Alo, Bhi, Blo, buf1, nullptr);

    // diagonal complex scan over T (scan3 in place: buf1 := [h_re | -h_im])
    scan1<<<256, 256, 0, stream>>>(buf1, nu + l * DHID, th + l * DHID, gl + l * DHID);
    scan2<<<4, 256, 0, stream>>>(buf1, ccre, ccim, nu + l * DHID, th + l * DHID);
    scan3<<<256, 256, 0, stream>>>(buf1, ccre, ccim, nu + l * DHID, th + l * DHID);

    // y = [h_re|-h_im] @ [C_re|C_im]^T (col-split at 1024, ldb=1024) -> buf1
    convert_hilo<<<gcA, 256, 0, stream>>>(buf1, buf1, 2048, BIG, BIG, Ahi, Alo);
    convert_hilo<<<gcW, 256, 0, stream>>>(Crl, Cil, 1024, BIG, 1024, Bhi, Blo);
    gemm_mfma<<<gg, 256, 0, stream>>>(Ahi, Alo, Bhi, Blo, buf1, nullptr);

    // g = gelu(y + xn*d): fused elementwise + A-convert (hi/lo only)
    e1_convert<<<gcA, 256, 0, stream>>>(buf1, act, Dd + l * DMODEL, Ahi, Alo);

    // t1 = g @ w1^T -> buf1 ; t2 = g @ w2^T -> act
    convert_hilo<<<gcW, 256, 0, stream>>>(w1l, w1l, 2048, BIG, BIG, Bhi, Blo);
    gemm_mfma<<<gg, 256, 0, stream>>>(Ahi, Alo, Bhi, Blo, buf1, nullptr);
    convert_hilo<<<gcW, 256, 0, stream>>>(w2l, w2l, 2048, BIG, BIG, Bhi, Blo);
    gemm_mfma<<<gg, 256, 0, stream>>>(Ahi, Alo, Bhi, Blo, act, nullptr);

    // carry += (t1+b1)*sigmoid(t2+b2)
    e2_kernel<<<EW, 256, 0, stream>>>(carry, buf1, act, b1 + l * DMODEL, b2 + l * DMODEL);
  }

  finalize<<<EW, 256, 0, stream>>>(carry, out);
}

// Round 4
// 2192.629 us; speedup vs baseline: 5.4055x; 1.0589x over previous
//
#include <hip/hip_runtime.h>
#include <stdint.h>
#include <math.h>

// ============================================================================
// StackedEncoderModel, round 8.
//  - Round 7's register-pipelined K-loop had a WAR bug: M23 (finishing tile
//    kt) ran AFTER RD_B overwrote the single B register set with tile kt+1's
//    fragments -> rows 32-63 of each wave tile used the wrong K-slice
//    (absmax 5.48). Fix: DUAL B register sets (B0/B1) alternating per K-step;
//    M23 of tile kt reads set p while RD_B fills set p^1.
//  - Schedule per K-step: {ds_read A23(p) || MFMA m01(p)} -> lgkmcnt(0)+bar ->
//    STAGE(p, kt+2) -> vmcnt(8)+bar -> {ds_read A01,B(p^1) || MFMA m23(p)}.
//    Counted vmcnt keeps 8-16 global_load_lds in flight; every ds_read burst
//    hides under a 24-MFMA burst.
//  - GLU fused into GEMM epilogues (epi=1 sigmoid, epi=2 carry+=(acc+b)*aux).
// ============================================================================

#define LAYERS 4
#define TT     4096
#define DMODEL 2048
#define DHID   1024
#define NCHUNK 64
#define CLEN   64   // TT / NCHUNK
#define KTILES 64   // 2048 / 32

typedef unsigned short ushort_t;
typedef __attribute__((ext_vector_type(8))) short  short8;
typedef __attribute__((ext_vector_type(4))) float  f32x4;

__device__ __forceinline__ ushort_t bf16_rne(float v) {
  unsigned b = __float_as_uint(v);
  return (ushort_t)((b + 0x7FFFu + ((b >> 16) & 1u)) >> 16);
}

// ----------------------------------------------------------------------------
// convert_hilo: fp32 source (with B0/B1/NS/KS split addressing) -> bf16 hi/lo
// in tiled layout: tile (mb,kb) = 128 rows x 32 k, stored [kg][m][j] bf16.
// ----------------------------------------------------------------------------
__global__ __launch_bounds__(256)
void convert_hilo(const float* __restrict__ B0, const float* __restrict__ B1,
                  int ldb, int NS, int KS,
                  ushort_t* __restrict__ Hi, ushort_t* __restrict__ Lo)
{
  __shared__ float tile[128][33];
  const int mb  = blockIdx.x;
  const int kb  = blockIdx.y;
  const int tid = threadIdx.x;
  const int r0  = tid >> 3;          // 0..31
  const int c0  = (tid & 7) * 4;     // 0..28
#pragma unroll
  for (int rep = 0; rep < 4; ++rep) {
    const int rr = rep * 32 + r0;
    const int n  = mb * 128 + rr;
    const int k  = kb * 32 + c0;
    const float* bp; long idx;
    if (n >= NS)      { bp = B1; idx = (long)(n - NS) * ldb + k; }
    else if (k >= KS) { bp = B1; idx = (long)n * ldb + (k - KS); }
    else              { bp = B0; idx = (long)n * ldb + k; }
#pragma unroll
    for (int u = 0; u < 4; ++u) tile[rr][c0 + u] = bp[idx + u];
  }
  __syncthreads();
#pragma unroll
  for (int rep = 0; rep < 2; ++rep) {
    const int id2 = rep * 256 + tid;
    const int kg  = id2 >> 7;        // 0..3
    const int m   = id2 & 127;
    unsigned hw[4], lw[4];
#pragma unroll
    for (int p = 0; p < 4; ++p) {
      unsigned hpair = 0, lpair = 0;
#pragma unroll
      for (int e = 0; e < 2; ++e) {
        const float v = tile[m][kg * 8 + p * 2 + e];
        const ushort_t h = bf16_rne(v);
        const float hf = __uint_as_float(((unsigned)h) << 16);
        const ushort_t l = bf16_rne(v - hf);
        hpair |= ((unsigned)h) << (16 * e);
        lpair |= ((unsigned)l) << (16 * e);
      }
      hw[p] = hpair; lw[p] = lpair;
    }
    const long off = ((long)mb * KTILES + kb) * 4096 + (kg * 128 + m) * 8;
    *(uint4*)&Hi[off] = make_uint4(hw[0], hw[1], hw[2], hw[3]);
    *(uint4*)&Lo[off] = make_uint4(lw[0], lw[1], lw[2], lw[3]);
  }
}

// ----------------------------------------------------------------------------
// bn_convert: BN-apply fused with hi/lo tiling. Writes act (xn fp32) + tiles.
// ----------------------------------------------------------------------------
__global__ __launch_bounds__(256)
void bn_convert(const float* __restrict__ carry, const float* __restrict__ stats,
                const float* __restrict__ nw, const float* __restrict__ nb,
                float* __restrict__ act,
                ushort_t* __restrict__ Hi, ushort_t* __restrict__ Lo)
{
  __shared__ float tile[128][33];
  const int mb  = blockIdx.x;
  const int kb  = blockIdx.y;
  const int tid = threadIdx.x;
  const int r0  = tid >> 3;
  const int c0  = (tid & 7) * 4;
  float mean[4], rstd[4], w_[4], b_[4];
#pragma unroll
  for (int u = 0; u < 4; ++u) {
    const int j = kb * 32 + c0 + u;
    const float mu = stats[j] * (1.0f / TT);
    const float va = fmaxf(stats[DMODEL + j] * (1.0f / TT) - mu * mu, 0.0f);
    mean[u] = mu; rstd[u] = rsqrtf(va + 1e-5f);
    w_[u] = nw[j]; b_[u] = nb[j];
  }
#pragma unroll
  for (int rep = 0; rep < 4; ++rep) {
    const int rr  = rep * 32 + r0;
    const long base = (long)(mb * 128 + rr) * 2048 + kb * 32 + c0;
#pragma unroll
    for (int u = 0; u < 4; ++u) {
      const float v = (carry[base + u] - mean[u]) * rstd[u] * w_[u] + b_[u];
      tile[rr][c0 + u] = v;
      act[base + u] = v;
    }
  }
  __syncthreads();
#pragma unroll
  for (int rep = 0; rep < 2; ++rep) {
    const int id2 = rep * 256 + tid;
    const int kg  = id2 >> 7;
    const int m   = id2 & 127;
    unsigned hw[4], lw[4];
#pragma unroll
    for (int p = 0; p < 4; ++p) {
      unsigned hpair = 0, lpair = 0;
#pragma unroll
      for (int e = 0; e < 2; ++e) {
        const float v = tile[m][kg * 8 + p * 2 + e];
        const ushort_t h = bf16_rne(v);
        const float hf = __uint_as_float(((unsigned)h) << 16);
        const ushort_t l = bf16_rne(v - hf);
        hpair |= ((unsigned)h) << (16 * e);
        lpair |= ((unsigned)l) << (16 * e);
      }
      hw[p] = hpair; lw[p] = lpair;
    }
    const long off = ((long)mb * KTILES + kb) * 4096 + (kg * 128 + m) * 8;
    *(uint4*)&Hi[off] = make_uint4(hw[0], hw[1], hw[2], hw[3]);
    *(uint4*)&Lo[off] = make_uint4(lw[0], lw[1], lw[2], lw[3]);
  }
}

// ----------------------------------------------------------------------------
// e1_convert: g = gelu(y + xn*d), emitted ONLY as tiled hi/lo.
// ----------------------------------------------------------------------------
__global__ __launch_bounds__(256)
void e1_convert(const float* __restrict__ y, const float* __restrict__ xn,
                const float* __restrict__ d,
                ushort_t* __restrict__ Hi, ushort_t* __restrict__ Lo)
{
  __shared__ float tile[128][33];
  const int mb  = blockIdx.x;
  const int kb  = blockIdx.y;
  const int tid = threadIdx.x;
  const int r0  = tid >> 3;
  const int c0  = (tid & 7) * 4;
  float dv[4];
#pragma unroll
  for (int u = 0; u < 4; ++u) dv[u] = d[kb * 32 + c0 + u];
#pragma unroll
  for (int rep = 0; rep < 4; ++rep) {
    const int rr  = rep * 32 + r0;
    const long base = (long)(mb * 128 + rr) * 2048 + kb * 32 + c0;
#pragma unroll
    for (int u = 0; u < 4; ++u) {
      const float v = y[base + u] + xn[base + u] * dv[u];
      tile[rr][c0 + u] = 0.5f * v * (1.0f + erff(v * 0.70710678118654752440f));
    }
  }
  __syncthreads();
#pragma unroll
  for (int rep = 0; rep < 2; ++rep) {
    const int id2 = rep * 256 + tid;
    const int kg  = id2 >> 7;
    const int m   = id2 & 127;
    unsigned hw[4], lw[4];
#pragma unroll
    for (int p = 0; p < 4; ++p) {
      unsigned hpair = 0, lpair = 0;
#pragma unroll
      for (int e = 0; e < 2; ++e) {
        const float v = tile[m][kg * 8 + p * 2 + e];
        const ushort_t h = bf16_rne(v);
        const float hf = __uint_as_float(((unsigned)h) << 16);
        const ushort_t l = bf16_rne(v - hf);
        hpair |= ((unsigned)h) << (16 * e);
        lpair |= ((unsigned)l) << (16 * e);
      }
      hw[p] = hpair; lw[p] = lpair;
    }
    const long off = ((long)mb * KTILES + kb) * 4096 + (kg * 128 + m) * 8;
    *(uint4*)&Hi[off] = make_uint4(hw[0], hw[1], hw[2], hw[3]);
    *(uint4*)&Lo[off] = make_uint4(lw[0], lw[1], lw[2], lw[3]);
  }
}

// ----------------------------------------------------------------------------
// MFMA split-precision GEMM, register-pipelined, dual-B. Grid (32,16).
// epi: 0 = C=acc+bias(optional)  1 = C=sigmoid(acc+bias)  2 = C+=(acc+bias)*aux
// ----------------------------------------------------------------------------
#define GLDS(gp, lp) __builtin_amdgcn_global_load_lds( \
    (__attribute__((address_space(1))) void*)(void*)(gp), \
    (__attribute__((address_space(3))) void*)(lp), 16, 0, 0)

__global__ __launch_bounds__(256)
void gemm_mfma(const ushort_t* __restrict__ Ahi, const ushort_t* __restrict__ Alo,
               const ushort_t* __restrict__ Bhi, const ushort_t* __restrict__ Blo,
               float* __restrict__ C, const float* __restrict__ bias,
               int epi, const float* __restrict__ aux)
{
  __shared__ ushort_t As_h[2][4096], As_l[2][4096], Bs_h[2][4096], Bs_l[2][4096];
  const int tid  = threadIdx.x;
  const int lane = tid & 63;
  const int wid  = tid >> 6;
  const int wm   = wid >> 1;
  const int wn   = wid & 1;
  const int mb   = blockIdx.x;
  const int nb   = blockIdx.y;

  f32x4 acc[4][4];
#pragma unroll
  for (int i = 0; i < 4; ++i)
#pragma unroll
    for (int j = 0; j < 4; ++j) acc[i][j] = (f32x4){0.f, 0.f, 0.f, 0.f};

  const ushort_t* ga_h = Ahi + (long)mb * KTILES * 4096 + tid * 8;
  const ushort_t* ga_l = Alo + (long)mb * KTILES * 4096 + tid * 8;
  const ushort_t* gb_h = Bhi + (long)nb * KTILES * 4096 + tid * 8;
  const ushort_t* gb_l = Blo + (long)nb * KTILES * 4096 + tid * 8;

  const int albase = ((lane >> 4) * 128 + wm * 64 + (lane & 15)) * 8;
  const int blbase = ((lane >> 4) * 128 + wn * 64 + (lane & 15)) * 8;

  short8 A01h[2], A01l[2], A23h[2], A23l[2];
  short8 B0h[4], B0l[4], B1h[4], B1l[4];   // dual B sets (the round-7 fix)

#define STAGE(p) \
  GLDS(ga_h,        &As_h[p][tid * 8]); \
  GLDS(ga_h + 2048, &As_h[p][2048 + tid * 8]); \
  GLDS(ga_l,        &As_l[p][tid * 8]); \
  GLDS(ga_l + 2048, &As_l[p][2048 + tid * 8]); \
  GLDS(gb_h,        &Bs_h[p][tid * 8]); \
  GLDS(gb_h + 2048, &Bs_h[p][2048 + tid * 8]); \
  GLDS(gb_l,        &Bs_l[p][tid * 8]); \
  GLDS(gb_l + 2048, &Bs_l[p][2048 + tid * 8]); \
  ga_h += 4096; ga_l += 4096; gb_h += 4096; gb_l += 4096;

#define RD_A01(p) \
  A01h[0] = *(const short8*)&As_h[p][albase];       A01l[0] = *(const short8*)&As_l[p][albase]; \
  A01h[1] = *(const short8*)&As_h[p][albase + 128]; A01l[1] = *(const short8*)&As_l[p][albase + 128];

#define RD_A23(p) \
  A23h[0] = *(const short8*)&As_h[p][albase + 256]; A23l[0] = *(const short8*)&As_l[p][albase + 256]; \
  A23h[1] = *(const short8*)&As_h[p][albase + 384]; A23l[1] = *(const short8*)&As_l[p][albase + 384];

#define RD_B(p, S) \
  _Pragma("unroll") \
  for (int n = 0; n < 4; ++n) { \
    S##h[n] = *(const short8*)&Bs_h[p][blbase + n * 128]; \
    S##l[n] = *(const short8*)&Bs_l[p][blbase + n * 128]; \
  }

#define MFMA3(m, ah, al, S) \
  _Pragma("unroll") \
  for (int n = 0; n < 4; ++n) { \
    acc[m][n] = __builtin_amdgcn_mfma_f32_16x16x32_bf16(ah, S##h[n], acc[m][n], 0, 0, 0); \
    acc[m][n] = __builtin_amdgcn_mfma_f32_16x16x32_bf16(al, S##h[n], acc[m][n], 0, 0, 0); \
    acc[m][n] = __builtin_amdgcn_mfma_f32_16x16x32_bf16(ah, S##l[n], acc[m][n], 0, 0, 0); \
  }

#define M01(S) __builtin_amdgcn_s_setprio(1); \
  MFMA3(0, A01h[0], A01l[0], S) MFMA3(1, A01h[1], A01l[1], S) \
  __builtin_amdgcn_s_setprio(0);
#define M23(S) __builtin_amdgcn_s_setprio(1); \
  MFMA3(2, A23h[0], A23l[0], S) MFMA3(3, A23h[1], A23l[1], S) \
  __builtin_amdgcn_s_setprio(0);

#define WAIT_LGKM0 asm volatile("s_waitcnt lgkmcnt(0)" ::: "memory"); \
  __builtin_amdgcn_sched_barrier(0); __builtin_amdgcn_s_barrier();
#define WAIT_VM(n) asm volatile("s_waitcnt vmcnt(" #n ")" ::: "memory"); \
  __builtin_amdgcn_sched_barrier(0); __builtin_amdgcn_s_barrier();

  // Prologue: stage tiles 0 and 1; wait for tile 0 (oldest 8 of 16 in flight).
  STAGE(0)
  STAGE(1)
  WAIT_VM(8)
  RD_A01(0) RD_B(0, B0)

  // Main: 31 iterations x 2 K-steps, stages tiles 2..63.
  for (int it = 0; it < 31; ++it) {
    // K-step: tile 2it in buf0, B in set B0
    RD_A23(0)
    M01(B0)
    WAIT_LGKM0           // all waves done reading buf0; safe to overwrite
    STAGE(0)             // tile 2it+2 -> buf0
    WAIT_VM(8)           // tile 2it+1 (buf1) landed in all waves
    RD_A01(1) RD_B(1, B1)
    M23(B0)              // finish tile 2it with its OWN B set
    // K-step: tile 2it+1 in buf1, B in set B1
    RD_A23(1)
    M01(B1)
    WAIT_LGKM0
    STAGE(1)             // tile 2it+3 -> buf1
    WAIT_VM(8)           // tile 2it+2 (buf0) landed
    RD_A01(0) RD_B(0, B0)
    M23(B1)
  }
  // Drain: tile 62 in buf0 (B0 loaded), tile 63 in buf1 (8 loads outstanding).
  RD_A23(0)
  M01(B0)
  WAIT_VM(0)             // tile 63 landed
  RD_A01(1) RD_B(1, B1)
  M23(B0)
  RD_A23(1)
  M01(B1)
  M23(B1)
#undef STAGE
#undef RD_A01
#undef RD_A23
#undef RD_B
#undef MFMA3
#undef M01
#undef M23
#undef WAIT_LGKM0
#undef WAIT_VM

  // C/D layout (HW-verified): col = lane&15, row = (lane>>4)*4 + reg
  const int cn = lane & 15;
  const int cr = (lane >> 4) * 4;
#pragma unroll
  for (int m = 0; m < 4; ++m) {
    const long row = (long)mb * 128 + wm * 64 + m * 16 + cr;
#pragma unroll
    for (int n = 0; n < 4; ++n) {
      const int col = nb * 128 + wn * 64 + n * 16 + cn;
      const float bv = bias ? bias[col] : 0.0f;
      if (epi == 0) {
#pragma unroll
        for (int q = 0; q < 4; ++q)
          C[(row + q) * 2048 + col] = acc[m][n][q] + bv;
      } else if (epi == 1) {
#pragma unroll
        for (int q = 0; q < 4; ++q)
          C[(row + q) * 2048 + col] = 1.0f / (1.0f + expf(-(acc[m][n][q] + bv)));
      } else {
#pragma unroll
        for (int q = 0; q < 4; ++q) {
          const long idx = (row + q) * 2048 + col;
          C[idx] += (acc[m][n][q] + bv) * aux[idx];
        }
      }
    }
  }
}

// ---------------------------------------------------------------------------
// BatchNorm partial sums.
// ---------------------------------------------------------------------------
__global__ void bn_partial(const float* __restrict__ carry, float* __restrict__ stats)
{
  const int j  = blockIdx.x * 256 + threadIdx.x;
  const int r0 = blockIdx.y * 128;
  float s = 0.f, ss = 0.f;
  for (int r = 0; r < 128; ++r) {
    float v = carry[(long)(r0 + r) * DMODEL + j];
    s += v; ss += v * v;
  }
  atomicAdd(&stats[j], s);
  atomicAdd(&stats[DMODEL + j], ss);
}

// ---------------------------------------------------------------------------
// LRU blocked scan. Bu layout: fp32 [T][2048], cols 0:1024 re, 1024:2048 im.
// ---------------------------------------------------------------------------
__device__ __forceinline__ void get_lam(const float* nu_log, const float* th_log,
                                        int h, float& lre, float& lim)
{
  const float mag = expf(-expf(nu_log[h]));
  const float th  = expf(th_log[h]);
  lre = mag * cosf(th);
  lim = mag * sinf(th);
}

__global__ void scan1(float* __restrict__ bu,
                      const float* __restrict__ nu_log, const float* __restrict__ th_log,
                      const float* __restrict__ gl_log)
{
  const int gid = blockIdx.x * 256 + threadIdx.x;
  const int c = gid >> 10, h = gid & 1023;
  float lre, lim; get_lam(nu_log, th_log, h, lre, lim);
  const float gamma = expf(gl_log[h]);
  float hr = 0.f, hi = 0.f;
  for (int i = 0; i < CLEN; ++i) {
    const long t = (long)c * CLEN + i;
    const float br_ = bu[t * 2048 + h] * gamma;
    const float bi_ = bu[t * 2048 + 1024 + h] * gamma;
    const float nr = lre * hr - lim * hi + br_;
    const float ni = lre * hi + lim * hr + bi_;
    hr = nr; hi = ni;
    bu[t * 2048 + h] = hr;
    bu[t * 2048 + 1024 + h] = hi;
  }
}

__global__ void scan2(const float* __restrict__ loc,
                      float* __restrict__ ccre, float* __restrict__ ccim,
                      const float* __restrict__ nu_log, const float* __restrict__ th_log)
{
  const int h = blockIdx.x * 256 + threadIdx.x;  // 0..1023
  float lre, lim; get_lam(nu_log, th_log, h, lre, lim);
  float ar = lre, ai = lim;                       // lam^64 via 6 squarings
  for (int s = 0; s < 6; ++s) { float nr = ar * ar - ai * ai, ni = 2.f * ar * ai; ar = nr; ai = ni; }
  float er = 0.f, ei = 0.f;
  for (int c = 0; c < NCHUNK; ++c) {
    ccre[c * DHID + h] = er; ccim[c * DHID + h] = ei;
    const long t = (long)c * CLEN + (CLEN - 1);
    const float nr = ar * er - ai * ei + loc[t * 2048 + h];
    const float ni = ar * ei + ai * er + loc[t * 2048 + 1024 + h];
    er = nr; ei = ni;
  }
}

// scan3 runs IN PLACE on loc, leaving [h_re | -h_im] for the C-projection.
__global__ void scan3(float* __restrict__ loc,
                      const float* __restrict__ ccre, const float* __restrict__ ccim,
                      const float* __restrict__ nu_log, const float* __restrict__ th_log)
{
  const int gid = blockIdx.x * 256 + threadIdx.x;
  const int c = gid >> 10, h = gid & 1023;
  float lre, lim; get_lam(nu_log, th_log, h, lre, lim);
  const float cr_ = ccre[c * DHID + h], ci_ = ccim[c * DHID + h];
  float pr = lre, pi = lim;   // lam^(i+1)
  for (int i = 0; i < CLEN; ++i) {
    const long t = (long)c * CLEN + i;
    const float hre = loc[t * 2048 + h]        + pr * cr_ - pi * ci_;
    const float him = loc[t * 2048 + 1024 + h] + pr * ci_ + pi * cr_;
    const float npr = pr * lre - pi * lim, npi = pr * lim + pi * lre;
    pr = npr; pi = npi;
    loc[t * 2048 + h]        = hre;
    loc[t * 2048 + 1024 + h] = -him;
  }
}

// ---------------------------------------------------------------------------
__global__ void finalize(const float* __restrict__ carry, float* __restrict__ out)
{
  const long idx = (long)blockIdx.x * 256 + threadIdx.x;
  const float v = carry[idx];
  out[idx] = (v == v && fabsf(v) < 3.0e38f) ? v : 300000.0f;
}

__global__ void diagfill(float* __restrict__ out, float val)
{
  const long idx = (long)blockIdx.x * 256 + threadIdx.x;
  out[idx] = (idx == 0) ? val : 0.0f;
}

// ---------------------------------------------------------------------------
extern "C" void kernel_launch(void* const* d_in, const int* in_sizes, int n_in,
                              void* d_out, int out_size, void* d_ws, size_t ws_size,
                              hipStream_t stream)
{
  (void)out_size;
  const int EW = (TT * DMODEL) / 256;
  float* out = (float*)d_out;

  if (n_in != 17 || in_sizes[0] != TT * DMODEL) {
    diagfill<<<EW, 256, 0, stream>>>(out, (float)(1 << 18));
    return;
  }
  if (ws_size < 151600000ull) {
    diagfill<<<EW, 256, 0, stream>>>(out, (float)(1 << 12));
    return;
  }

  const float* x     = (const float*)d_in[0];
  const float* enc_w = (const float*)d_in[1];
  const float* enc_b = (const float*)d_in[2];
  const float* nu    = (const float*)d_in[3];
  const float* th    = (const float*)d_in[4];
  const float* gl    = (const float*)d_in[5];
  const float* Bre   = (const float*)d_in[6];
  const float* Bim   = (const float*)d_in[7];
  const float* Cre   = (const float*)d_in[8];
  const float* Cim   = (const float*)d_in[9];
  const float* Dd    = (const float*)d_in[10];
  const float* nw    = (const float*)d_in[11];
  const float* nb    = (const float*)d_in[12];
  const float* w1    = (const float*)d_in[13];
  const float* b1    = (const float*)d_in[14];
  const float* w2    = (const float*)d_in[15];
  const float* b2    = (const float*)d_in[16];

  char* ws = (char*)d_ws;
  float*    carry = (float*)(ws);                 // [T][DM] residual stream
  float*    act   = (float*)(ws + 33554432);      // xn -> sig(t2)
  float*    buf1  = (float*)(ws + 67108864);      // Bu -> ah -> y
  ushort_t* Ahi   = (ushort_t*)(ws + 100663296);  // tiled bf16 hi of A operand
  ushort_t* Alo   = (ushort_t*)(ws + 117440512);
  ushort_t* Bhi   = (ushort_t*)(ws + 134217728);  // tiled bf16 hi of B operand
  ushort_t* Blo   = (ushort_t*)(ws + 142606336);
  float*    ccre  = (float*)(ws + 150994944);
  float*    ccim  = (float*)(ws + 151257088);
  float*    stats = (float*)(ws + 151519232);

  const dim3 gcA(32, 64);   // 4096-row operand, 64 k-tiles
  const dim3 gcW(16, 64);   // 2048-row operand
  const dim3 gg(32, 16);    // GEMM: 32 m-blocks x 16 n-blocks
  const int BIG = 1 << 30;

  // encoder: carry = x @ enc_w^T + enc_b
  convert_hilo<<<gcA, 256, 0, stream>>>(x, x, 2048, BIG, BIG, Ahi, Alo);
  convert_hilo<<<gcW, 256, 0, stream>>>(enc_w, enc_w, 2048, BIG, BIG, Bhi, Blo);
  gemm_mfma<<<gg, 256, 0, stream>>>(Ahi, Alo, Bhi, Blo, carry, enc_b, 0, nullptr);

  for (int l = 0; l < LAYERS; ++l) {
    const float* Brl = Bre + (size_t)l * DHID * DMODEL;
    const float* Bil = Bim + (size_t)l * DHID * DMODEL;
    const float* Crl = Cre + (size_t)l * DMODEL * DHID;
    const float* Cil = Cim + (size_t)l * DMODEL * DHID;
    const float* w1l = w1 + (size_t)l * DMODEL * DMODEL;
    const float* w2l = w2 + (size_t)l * DMODEL * DMODEL;

    // BatchNorm stats, then fused BN-apply + A-convert (act=xn + Ahi/Alo)
    hipMemsetAsync(stats, 0, 2 * DMODEL * sizeof(float), stream);
    bn_partial<<<dim3(DMODEL / 256, TT / 128), 256, 0, stream>>>(carry, stats);
    bn_convert<<<gcA, 256, 0, stream>>>(carry, stats, nw + l * DMODEL, nb + l * DMODEL,
                                        act, Ahi, Alo);

    // Bu = xn @ [B_re; B_im]^T  (row-split at 1024) -> buf1 [re|im]
    convert_hilo<<<gcW, 256, 0, stream>>>(Brl, Bil, 2048, 1024, BIG, Bhi, Blo);
    gemm_mfma<<<gg, 256, 0, stream>>>(Ahi, Alo, Bhi, Blo, buf1, nullptr, 0, nullptr);

    // diagonal complex scan over T (scan3 in place: buf1 := [h_re | -h_im])
    scan1<<<256, 256, 0, stream>>>(buf1, nu + l * DHID, th + l * DHID, gl + l * DHID);
    scan2<<<4, 256, 0, stream>>>(buf1, ccre, ccim, nu + l * DHID, th + l * DHID);
    scan3<<<256, 256, 0, stream>>>(buf1, ccre, ccim, nu + l * DHID, th + l * DHID);

    // y = [h_re|-h_im] @ [C_re|C_im]^T (col-split at 1024, ldb=1024) -> buf1
    convert_hilo<<<gcA, 256, 0, stream>>>(buf1, buf1, 2048, BIG, BIG, Ahi, Alo);
    convert_hilo<<<gcW, 256, 0, stream>>>(Crl, Cil, 1024, BIG, 1024, Bhi, Blo);
    gemm_mfma<<<gg, 256, 0, stream>>>(Ahi, Alo, Bhi, Blo, buf1, nullptr, 0, nullptr);

    // g = gelu(y + xn*d): fused elementwise + A-convert (hi/lo only)
    e1_convert<<<gcA, 256, 0, stream>>>(buf1, act, Dd + l * DMODEL, Ahi, Alo);

    // t2 first: act := sigmoid(g @ w2^T + b2)   (fused epilogue)
    convert_hilo<<<gcW, 256, 0, stream>>>(w2l, w2l, 2048, BIG, BIG, Bhi, Blo);
    gemm_mfma<<<gg, 256, 0, stream>>>(Ahi, Alo, Bhi, Blo, act, b2 + l * DMODEL, 1, nullptr);

    // t1: carry += (g @ w1^T + b1) * act       (fused epilogue)
    convert_hilo<<<gcW, 256, 0, stream>>>(w1l, w1l, 2048, BIG, BIG, Bhi, Blo);
    gemm_mfma<<<gg, 256, 0, stream>>>(Ahi, Alo, Bhi, Blo, carry, b1 + l * DMODEL, 2, act);
  }

  finalize<<<EW, 256, 0, stream>>>(carry, out);
}

// Round 5
// 1954.043 us; speedup vs baseline: 6.0655x; 1.1221x over previous
//
#include <hip/hip_runtime.h>
#include <stdint.h>
#include <math.h>

// ============================================================================
// StackedEncoderModel, round 9.
//  - Precision scheme: fp16 2-term split (was bf16 3-term). A = Ah+Al (fp16),
//    B = Bh (fp16). C = Ah*Bh + Al*Bh = A*fp16(B); dropped Ah*Bl term is
//    ~2^-11 relative (fp16 11-bit mantissa). Cuts MFMA/step 48->32, ds_read
//    16->12, GLDS 8->6, LDS 64->48KB, B traffic -50%.
//  - Same register-pipelined dual-B K-loop as round 8 (verified), with vmcnt
//    counts 8->6.
//  - XCD-aware block swizzle: bid%8 = XCD gets a contiguous 8x8 tile region.
//  - GLU fused epilogues (epi=1 sigmoid, epi=2 carry+=(acc+b)*aux) retained.
// ============================================================================

#define LAYERS 4
#define TT     4096
#define DMODEL 2048
#define DHID   1024
#define NCHUNK 64
#define CLEN   64   // TT / NCHUNK
#define KTILES 64   // 2048 / 32

typedef unsigned short ushort_t;
typedef __attribute__((ext_vector_type(8))) _Float16 half8;
typedef __attribute__((ext_vector_type(4))) float    f32x4;

// pack two floats as adjacent fp16 (RNE) into one dword
__device__ __forceinline__ unsigned pack2h(float a, float b) {
  _Float16 ha = (_Float16)a, hb = (_Float16)b;
  unsigned short ua = *(unsigned short*)&ha, ub = *(unsigned short*)&hb;
  return (unsigned)ua | ((unsigned)ub << 16);
}
__device__ __forceinline__ float lo_res(float v) {
  _Float16 h = (_Float16)v;
  return v - (float)h;
}

// ----------------------------------------------------------------------------
// convert_hilo: fp32 source (with B0/B1/NS/KS split addressing) -> fp16 hi
// (+ optional lo) in tiled layout: tile (mb,kb) = 128 rows x 32 k, stored
// [kg 0..3][m 0..127][j 0..7] fp16, 8KB per tile.
// ----------------------------------------------------------------------------
__global__ __launch_bounds__(256)
void convert_hilo(const float* __restrict__ B0, const float* __restrict__ B1,
                  int ldb, int NS, int KS,
                  ushort_t* __restrict__ Hi, ushort_t* __restrict__ Lo)
{
  __shared__ float tile[128][33];
  const int mb  = blockIdx.x;
  const int kb  = blockIdx.y;
  const int tid = threadIdx.x;
  const int r0  = tid >> 3;          // 0..31
  const int c0  = (tid & 7) * 4;     // 0..28
#pragma unroll
  for (int rep = 0; rep < 4; ++rep) {
    const int rr = rep * 32 + r0;
    const int n  = mb * 128 + rr;
    const int k  = kb * 32 + c0;
    const float* bp; long idx;
    if (n >= NS)      { bp = B1; idx = (long)(n - NS) * ldb + k; }
    else if (k >= KS) { bp = B1; idx = (long)n * ldb + (k - KS); }
    else              { bp = B0; idx = (long)n * ldb + k; }
#pragma unroll
    for (int u = 0; u < 4; ++u) tile[rr][c0 + u] = bp[idx + u];
  }
  __syncthreads();
#pragma unroll
  for (int rep = 0; rep < 2; ++rep) {
    const int id2 = rep * 256 + tid;
    const int kg  = id2 >> 7;        // 0..3
    const int m   = id2 & 127;
    const long off = ((long)mb * KTILES + kb) * 4096 + (kg * 128 + m) * 8;
    unsigned hw[4];
#pragma unroll
    for (int p = 0; p < 4; ++p)
      hw[p] = pack2h(tile[m][kg * 8 + p * 2], tile[m][kg * 8 + p * 2 + 1]);
    *(uint4*)&Hi[off] = make_uint4(hw[0], hw[1], hw[2], hw[3]);
    if (Lo) {
      unsigned lw[4];
#pragma unroll
      for (int p = 0; p < 4; ++p)
        lw[p] = pack2h(lo_res(tile[m][kg * 8 + p * 2]),
                       lo_res(tile[m][kg * 8 + p * 2 + 1]));
      *(uint4*)&Lo[off] = make_uint4(lw[0], lw[1], lw[2], lw[3]);
    }
  }
}

// ----------------------------------------------------------------------------
// bn_convert: BN-apply fused with fp16 hi/lo tiling. Writes act (xn fp32).
// ----------------------------------------------------------------------------
__global__ __launch_bounds__(256)
void bn_convert(const float* __restrict__ carry, const float* __restrict__ stats,
                const float* __restrict__ nw, const float* __restrict__ nb,
                float* __restrict__ act,
                ushort_t* __restrict__ Hi, ushort_t* __restrict__ Lo)
{
  __shared__ float tile[128][33];
  const int mb  = blockIdx.x;
  const int kb  = blockIdx.y;
  const int tid = threadIdx.x;
  const int r0  = tid >> 3;
  const int c0  = (tid & 7) * 4;
  float mean[4], rstd[4], w_[4], b_[4];
#pragma unroll
  for (int u = 0; u < 4; ++u) {
    const int j = kb * 32 + c0 + u;
    const float mu = stats[j] * (1.0f / TT);
    const float va = fmaxf(stats[DMODEL + j] * (1.0f / TT) - mu * mu, 0.0f);
    mean[u] = mu; rstd[u] = rsqrtf(va + 1e-5f);
    w_[u] = nw[j]; b_[u] = nb[j];
  }
#pragma unroll
  for (int rep = 0; rep < 4; ++rep) {
    const int rr  = rep * 32 + r0;
    const long base = (long)(mb * 128 + rr) * 2048 + kb * 32 + c0;
#pragma unroll
    for (int u = 0; u < 4; ++u) {
      const float v = (carry[base + u] - mean[u]) * rstd[u] * w_[u] + b_[u];
      tile[rr][c0 + u] = v;
      act[base + u] = v;
    }
  }
  __syncthreads();
#pragma unroll
  for (int rep = 0; rep < 2; ++rep) {
    const int id2 = rep * 256 + tid;
    const int kg  = id2 >> 7;
    const int m   = id2 & 127;
    const long off = ((long)mb * KTILES + kb) * 4096 + (kg * 128 + m) * 8;
    unsigned hw[4], lw[4];
#pragma unroll
    for (int p = 0; p < 4; ++p) {
      const float a = tile[m][kg * 8 + p * 2], b = tile[m][kg * 8 + p * 2 + 1];
      hw[p] = pack2h(a, b);
      lw[p] = pack2h(lo_res(a), lo_res(b));
    }
    *(uint4*)&Hi[off] = make_uint4(hw[0], hw[1], hw[2], hw[3]);
    *(uint4*)&Lo[off] = make_uint4(lw[0], lw[1], lw[2], lw[3]);
  }
}

// ----------------------------------------------------------------------------
// e1_convert: g = gelu(y + xn*d), emitted ONLY as tiled fp16 hi/lo.
// ----------------------------------------------------------------------------
__global__ __launch_bounds__(256)
void e1_convert(const float* __restrict__ y, const float* __restrict__ xn,
                const float* __restrict__ d,
                ushort_t* __restrict__ Hi, ushort_t* __restrict__ Lo)
{
  __shared__ float tile[128][33];
  const int mb  = blockIdx.x;
  const int kb  = blockIdx.y;
  const int tid = threadIdx.x;
  const int r0  = tid >> 3;
  const int c0  = (tid & 7) * 4;
  float dv[4];
#pragma unroll
  for (int u = 0; u < 4; ++u) dv[u] = d[kb * 32 + c0 + u];
#pragma unroll
  for (int rep = 0; rep < 4; ++rep) {
    const int rr  = rep * 32 + r0;
    const long base = (long)(mb * 128 + rr) * 2048 + kb * 32 + c0;
#pragma unroll
    for (int u = 0; u < 4; ++u) {
      const float v = y[base + u] + xn[base + u] * dv[u];
      tile[rr][c0 + u] = 0.5f * v * (1.0f + erff(v * 0.70710678118654752440f));
    }
  }
  __syncthreads();
#pragma unroll
  for (int rep = 0; rep < 2; ++rep) {
    const int id2 = rep * 256 + tid;
    const int kg  = id2 >> 7;
    const int m   = id2 & 127;
    const long off = ((long)mb * KTILES + kb) * 4096 + (kg * 128 + m) * 8;
    unsigned hw[4], lw[4];
#pragma unroll
    for (int p = 0; p < 4; ++p) {
      const float a = tile[m][kg * 8 + p * 2], b = tile[m][kg * 8 + p * 2 + 1];
      hw[p] = pack2h(a, b);
      lw[p] = pack2h(lo_res(a), lo_res(b));
    }
    *(uint4*)&Hi[off] = make_uint4(hw[0], hw[1], hw[2], hw[3]);
    *(uint4*)&Lo[off] = make_uint4(lw[0], lw[1], lw[2], lw[3]);
  }
}

// ----------------------------------------------------------------------------
// MFMA fp16 2-term GEMM, register-pipelined, dual-B, XCD-swizzled.
// Grid 512 blocks (launched (32,16)). epi: 0 = C=acc+bias  1 = sigmoid
// 2 = C += (acc+bias)*aux
// ----------------------------------------------------------------------------
#define GLDS(gp, lp) __builtin_amdgcn_global_load_lds( \
    (__attribute__((address_space(1))) void*)(void*)(gp), \
    (__attribute__((address_space(3))) void*)(lp), 16, 0, 0)

__global__ __launch_bounds__(256)
void gemm_mfma(const ushort_t* __restrict__ Ahi, const ushort_t* __restrict__ Alo,
               const ushort_t* __restrict__ Bhi,
               float* __restrict__ C, const float* __restrict__ bias,
               int epi, const float* __restrict__ aux)
{
  __shared__ ushort_t As_h[2][4096], As_l[2][4096], Bs_h[2][4096];
  const int tid  = threadIdx.x;
  const int lane = tid & 63;
  const int wid  = tid >> 6;
  const int wm   = wid >> 1;
  const int wn   = wid & 1;

  // XCD swizzle: bid%8 = XCD; each XCD gets a contiguous 8x8 tile region.
  const int bid = blockIdx.y * gridDim.x + blockIdx.x;
  const int xcd = bid & 7, idx = bid >> 3;
  const int mb  = ((xcd & 3) << 3) | (idx & 7);   // 0..31
  const int nb  = ((xcd >> 2) << 3) | (idx >> 3); // 0..15

  f32x4 acc[4][4];
#pragma unroll
  for (int i = 0; i < 4; ++i)
#pragma unroll
    for (int j = 0; j < 4; ++j) acc[i][j] = (f32x4){0.f, 0.f, 0.f, 0.f};

  const ushort_t* ga_h = Ahi + (long)mb * KTILES * 4096 + tid * 8;
  const ushort_t* ga_l = Alo + (long)mb * KTILES * 4096 + tid * 8;
  const ushort_t* gb_h = Bhi + (long)nb * KTILES * 4096 + tid * 8;

  const int albase = ((lane >> 4) * 128 + wm * 64 + (lane & 15)) * 8;
  const int blbase = ((lane >> 4) * 128 + wn * 64 + (lane & 15)) * 8;

  half8 A01h[2], A01l[2], A23h[2], A23l[2];
  half8 B0h[4], B1h[4];   // dual B register sets (one per LDS page)

#define STAGE(p) \
  GLDS(ga_h,        &As_h[p][tid * 8]); \
  GLDS(ga_h + 2048, &As_h[p][2048 + tid * 8]); \
  GLDS(ga_l,        &As_l[p][tid * 8]); \
  GLDS(ga_l + 2048, &As_l[p][2048 + tid * 8]); \
  GLDS(gb_h,        &Bs_h[p][tid * 8]); \
  GLDS(gb_h + 2048, &Bs_h[p][2048 + tid * 8]); \
  ga_h += 4096; ga_l += 4096; gb_h += 4096;

#define RD_A01(p) \
  A01h[0] = *(const half8*)&As_h[p][albase];       A01l[0] = *(const half8*)&As_l[p][albase]; \
  A01h[1] = *(const half8*)&As_h[p][albase + 128]; A01l[1] = *(const half8*)&As_l[p][albase + 128];

#define RD_A23(p) \
  A23h[0] = *(const half8*)&As_h[p][albase + 256]; A23l[0] = *(const half8*)&As_l[p][albase + 256]; \
  A23h[1] = *(const half8*)&As_h[p][albase + 384]; A23l[1] = *(const half8*)&As_l[p][albase + 384];

#define RD_B(p, S) \
  _Pragma("unroll") \
  for (int n = 0; n < 4; ++n) \
    S[n] = *(const half8*)&Bs_h[p][blbase + n * 128];

#define MFMA2(m, ah, al, S) \
  _Pragma("unroll") \
  for (int n = 0; n < 4; ++n) { \
    acc[m][n] = __builtin_amdgcn_mfma_f32_16x16x32_f16(ah, S[n], acc[m][n], 0, 0, 0); \
    acc[m][n] = __builtin_amdgcn_mfma_f32_16x16x32_f16(al, S[n], acc[m][n], 0, 0, 0); \
  }

#define M01(S) __builtin_amdgcn_s_setprio(1); \
  MFMA2(0, A01h[0], A01l[0], S) MFMA2(1, A01h[1], A01l[1], S) \
  __builtin_amdgcn_s_setprio(0);
#define M23(S) __builtin_amdgcn_s_setprio(1); \
  MFMA2(2, A23h[0], A23l[0], S) MFMA2(3, A23h[1], A23l[1], S) \
  __builtin_amdgcn_s_setprio(0);

#define WAIT_LGKM0 asm volatile("s_waitcnt lgkmcnt(0)" ::: "memory"); \
  __builtin_amdgcn_sched_barrier(0); __builtin_amdgcn_s_barrier();
#define WAIT_VM(n) asm volatile("s_waitcnt vmcnt(" #n ")" ::: "memory"); \
  __builtin_amdgcn_sched_barrier(0); __builtin_amdgcn_s_barrier();

  // Prologue: stage tiles 0,1 (12 loads in flight); wait for tile 0 (oldest 6).
  STAGE(0)
  STAGE(1)
  WAIT_VM(6)
  RD_A01(0) RD_B(0, B0h)

  // Main: 31 iterations x 2 K-steps, stages tiles 2..63.
  for (int it = 0; it < 31; ++it) {
    RD_A23(0)
    M01(B0h)
    WAIT_LGKM0           // all waves done reading buf0; safe to overwrite
    STAGE(0)             // tile 2it+2 -> buf0 (12 outstanding)
    WAIT_VM(6)           // tile 2it+1 (buf1) landed
    RD_A01(1) RD_B(1, B1h)
    M23(B0h)             // finish tile 2it with its own B set
    RD_A23(1)
    M01(B1h)
    WAIT_LGKM0
    STAGE(1)             // tile 2it+3 -> buf1
    WAIT_VM(6)           // tile 2it+2 (buf0) landed
    RD_A01(0) RD_B(0, B0h)
    M23(B1h)
  }
  // Drain: tile 62 (buf0) fragments loaded; tile 63 (buf1) 6 loads in flight.
  RD_A23(0)
  M01(B0h)
  WAIT_VM(0)             // tile 63 landed
  RD_A01(1) RD_B(1, B1h)
  M23(B0h)
  RD_A23(1)
  M01(B1h)
  M23(B1h)
#undef STAGE
#undef RD_A01
#undef RD_A23
#undef RD_B
#undef MFMA2
#undef M01
#undef M23
#undef WAIT_LGKM0
#undef WAIT_VM

  // C/D layout (HW-verified): col = lane&15, row = (lane>>4)*4 + reg
  const int cn = lane & 15;
  const int cr = (lane >> 4) * 4;
#pragma unroll
  for (int m = 0; m < 4; ++m) {
    const long row = (long)mb * 128 + wm * 64 + m * 16 + cr;
#pragma unroll
    for (int n = 0; n < 4; ++n) {
      const int col = nb * 128 + wn * 64 + n * 16 + cn;
      const float bv = bias ? bias[col] : 0.0f;
      if (epi == 0) {
#pragma unroll
        for (int q = 0; q < 4; ++q)
          C[(row + q) * 2048 + col] = acc[m][n][q] + bv;
      } else if (epi == 1) {
#pragma unroll
        for (int q = 0; q < 4; ++q)
          C[(row + q) * 2048 + col] = 1.0f / (1.0f + expf(-(acc[m][n][q] + bv)));
      } else {
#pragma unroll
        for (int q = 0; q < 4; ++q) {
          const long idx2 = (row + q) * 2048 + col;
          C[idx2] += (acc[m][n][q] + bv) * aux[idx2];
        }
      }
    }
  }
}

// ---------------------------------------------------------------------------
// BatchNorm partial sums.
// ---------------------------------------------------------------------------
__global__ void bn_partial(const float* __restrict__ carry, float* __restrict__ stats)
{
  const int j  = blockIdx.x * 256 + threadIdx.x;
  const int r0 = blockIdx.y * 128;
  float s = 0.f, ss = 0.f;
  for (int r = 0; r < 128; ++r) {
    float v = carry[(long)(r0 + r) * DMODEL + j];
    s += v; ss += v * v;
  }
  atomicAdd(&stats[j], s);
  atomicAdd(&stats[DMODEL + j], ss);
}

// ---------------------------------------------------------------------------
// LRU blocked scan. Bu layout: fp32 [T][2048], cols 0:1024 re, 1024:2048 im.
// ---------------------------------------------------------------------------
__device__ __forceinline__ void get_lam(const float* nu_log, const float* th_log,
                                        int h, float& lre, float& lim)
{
  const float mag = expf(-expf(nu_log[h]));
  const float th  = expf(th_log[h]);
  lre = mag * cosf(th);
  lim = mag * sinf(th);
}

__global__ void scan1(float* __restrict__ bu,
                      const float* __restrict__ nu_log, const float* __restrict__ th_log,
                      const float* __restrict__ gl_log)
{
  const int gid = blockIdx.x * 256 + threadIdx.x;
  const int c = gid >> 10, h = gid & 1023;
  float lre, lim; get_lam(nu_log, th_log, h, lre, lim);
  const float gamma = expf(gl_log[h]);
  float hr = 0.f, hi = 0.f;
  for (int i = 0; i < CLEN; ++i) {
    const long t = (long)c * CLEN + i;
    const float br_ = bu[t * 2048 + h] * gamma;
    const float bi_ = bu[t * 2048 + 1024 + h] * gamma;
    const float nr = lre * hr - lim * hi + br_;
    const float ni = lre * hi + lim * hr + bi_;
    hr = nr; hi = ni;
    bu[t * 2048 + h] = hr;
    bu[t * 2048 + 1024 + h] = hi;
  }
}

__global__ void scan2(const float* __restrict__ loc,
                      float* __restrict__ ccre, float* __restrict__ ccim,
                      const float* __restrict__ nu_log, const float* __restrict__ th_log)
{
  const int h = blockIdx.x * 256 + threadIdx.x;  // 0..1023
  float lre, lim; get_lam(nu_log, th_log, h, lre, lim);
  float ar = lre, ai = lim;                       // lam^64 via 6 squarings
  for (int s = 0; s < 6; ++s) { float nr = ar * ar - ai * ai, ni = 2.f * ar * ai; ar = nr; ai = ni; }
  float er = 0.f, ei = 0.f;
  for (int c = 0; c < NCHUNK; ++c) {
    ccre[c * DHID + h] = er; ccim[c * DHID + h] = ei;
    const long t = (long)c * CLEN + (CLEN - 1);
    const float nr = ar * er - ai * ei + loc[t * 2048 + h];
    const float ni = ar * ei + ai * er + loc[t * 2048 + 1024 + h];
    er = nr; ei = ni;
  }
}

// scan3 runs IN PLACE on loc, leaving [h_re | -h_im] for the C-projection.
__global__ void scan3(float* __restrict__ loc,
                      const float* __restrict__ ccre, const float* __restrict__ ccim,
                      const float* __restrict__ nu_log, const float* __restrict__ th_log)
{
  const int gid = blockIdx.x * 256 + threadIdx.x;
  const int c = gid >> 10, h = gid & 1023;
  float lre, lim; get_lam(nu_log, th_log, h, lre, lim);
  const float cr_ = ccre[c * DHID + h], ci_ = ccim[c * DHID + h];
  float pr = lre, pi = lim;   // lam^(i+1)
  for (int i = 0; i < CLEN; ++i) {
    const long t = (long)c * CLEN + i;
    const float hre = loc[t * 2048 + h]        + pr * cr_ - pi * ci_;
    const float him = loc[t * 2048 + 1024 + h] + pr * ci_ + pi * cr_;
    const float npr = pr * lre - pi * lim, npi = pr * lim + pi * lre;
    pr = npr; pi = npi;
    loc[t * 2048 + h]        = hre;
    loc[t * 2048 + 1024 + h] = -him;
  }
}

// ---------------------------------------------------------------------------
__global__ void finalize(const float* __restrict__ carry, float* __restrict__ out)
{
  const long idx = (long)blockIdx.x * 256 + threadIdx.x;
  const float v = carry[idx];
  out[idx] = (v == v && fabsf(v) < 3.0e38f) ? v : 300000.0f;
}

__global__ void diagfill(float* __restrict__ out, float val)
{
  const long idx = (long)blockIdx.x * 256 + threadIdx.x;
  out[idx] = (idx == 0) ? val : 0.0f;
}

// ---------------------------------------------------------------------------
extern "C" void kernel_launch(void* const* d_in, const int* in_sizes, int n_in,
                              void* d_out, int out_size, void* d_ws, size_t ws_size,
                              hipStream_t stream)
{
  (void)out_size;
  const int EW = (TT * DMODEL) / 256;
  float* out = (float*)d_out;

  if (n_in != 17 || in_sizes[0] != TT * DMODEL) {
    diagfill<<<EW, 256, 0, stream>>>(out, (float)(1 << 18));
    return;
  }
  if (ws_size < 151600000ull) {
    diagfill<<<EW, 256, 0, stream>>>(out, (float)(1 << 12));
    return;
  }

  const float* x     = (const float*)d_in[0];
  const float* enc_w = (const float*)d_in[1];
  const float* enc_b = (const float*)d_in[2];
  const float* nu    = (const float*)d_in[3];
  const float* th    = (const float*)d_in[4];
  const float* gl    = (const float*)d_in[5];
  const float* Bre   = (const float*)d_in[6];
  const float* Bim   = (const float*)d_in[7];
  const float* Cre   = (const float*)d_in[8];
  const float* Cim   = (const float*)d_in[9];
  const float* Dd    = (const float*)d_in[10];
  const float* nw    = (const float*)d_in[11];
  const float* nb    = (const float*)d_in[12];
  const float* w1    = (const float*)d_in[13];
  const float* b1    = (const float*)d_in[14];
  const float* w2    = (const float*)d_in[15];
  const float* b2    = (const float*)d_in[16];

  char* ws = (char*)d_ws;
  float*    carry = (float*)(ws);                 // [T][DM] residual stream
  float*    act   = (float*)(ws + 33554432);      // xn -> sig(t2)
  float*    buf1  = (float*)(ws + 67108864);      // Bu -> ah -> y
  ushort_t* Ahi   = (ushort_t*)(ws + 100663296);  // tiled fp16 hi of A operand
  ushort_t* Alo   = (ushort_t*)(ws + 117440512);
  ushort_t* Bhi   = (ushort_t*)(ws + 134217728);  // tiled fp16 hi of B operand
  float*    ccre  = (float*)(ws + 150994944);
  float*    ccim  = (float*)(ws + 151257088);
  float*    stats = (float*)(ws + 151519232);

  const dim3 gcA(32, 64);   // 4096-row operand, 64 k-tiles
  const dim3 gcW(16, 64);   // 2048-row operand
  const dim3 gg(32, 16);    // GEMM: 512 blocks (swizzled in-kernel)
  const int BIG = 1 << 30;

  // encoder: carry = x @ enc_w^T + enc_b
  convert_hilo<<<gcA, 256, 0, stream>>>(x, x, 2048, BIG, BIG, Ahi, Alo);
  convert_hilo<<<gcW, 256, 0, stream>>>(enc_w, enc_w, 2048, BIG, BIG, Bhi, nullptr);
  gemm_mfma<<<gg, 256, 0, stream>>>(Ahi, Alo, Bhi, carry, enc_b, 0, nullptr);

  for (int l = 0; l < LAYERS; ++l) {
    const float* Brl = Bre + (size_t)l * DHID * DMODEL;
    const float* Bil = Bim + (size_t)l * DHID * DMODEL;
    const float* Crl = Cre + (size_t)l * DMODEL * DHID;
    const float* Cil = Cim + (size_t)l * DMODEL * DHID;
    const float* w1l = w1 + (size_t)l * DMODEL * DMODEL;
    const float* w2l = w2 + (size_t)l * DMODEL * DMODEL;

    // BatchNorm stats, then fused BN-apply + A-convert (act=xn + Ahi/Alo)
    hipMemsetAsync(stats, 0, 2 * DMODEL * sizeof(float), stream);
    bn_partial<<<dim3(DMODEL / 256, TT / 128), 256, 0, stream>>>(carry, stats);
    bn_convert<<<gcA, 256, 0, stream>>>(carry, stats, nw + l * DMODEL, nb + l * DMODEL,
                                        act, Ahi, Alo);

    // Bu = xn @ [B_re; B_im]^T  (row-split at 1024) -> buf1 [re|im]
    convert_hilo<<<gcW, 256, 0, stream>>>(Brl, Bil, 2048, 1024, BIG, Bhi, nullptr);
    gemm_mfma<<<gg, 256, 0, stream>>>(Ahi, Alo, Bhi, buf1, nullptr, 0, nullptr);

    // diagonal complex scan over T (scan3 in place: buf1 := [h_re | -h_im])
    scan1<<<256, 256, 0, stream>>>(buf1, nu + l * DHID, th + l * DHID, gl + l * DHID);
    scan2<<<4, 256, 0, stream>>>(buf1, ccre, ccim, nu + l * DHID, th + l * DHID);
    scan3<<<256, 256, 0, stream>>>(buf1, ccre, ccim, nu + l * DHID, th + l * DHID);

    // y = [h_re|-h_im] @ [C_re|C_im]^T (col-split at 1024, ldb=1024) -> buf1
    convert_hilo<<<gcA, 256, 0, stream>>>(buf1, buf1, 2048, BIG, BIG, Ahi, Alo);
    convert_hilo<<<gcW, 256, 0, stream>>>(Crl, Cil, 1024, BIG, 1024, Bhi, nullptr);
    gemm_mfma<<<gg, 256, 0, stream>>>(Ahi, Alo, Bhi, buf1, nullptr, 0, nullptr);

    // g = gelu(y + xn*d): fused elementwise + A-convert (hi/lo only)
    e1_convert<<<gcA, 256, 0, stream>>>(buf1, act, Dd + l * DMODEL, Ahi, Alo);

    // t2 first: act := sigmoid(g @ w2^T + b2)   (fused epilogue)
    convert_hilo<<<gcW, 256, 0, stream>>>(w2l, w2l, 2048, BIG, BIG, Bhi, nullptr);
    gemm_mfma<<<gg, 256, 0, stream>>>(Ahi, Alo, Bhi, act, b2 + l * DMODEL, 1, nullptr);

    // t1: carry += (g @ w1^T + b1) * act       (fused epilogue)
    convert_hilo<<<gcW, 256, 0, stream>>>(w1l, w1l, 2048, BIG, BIG, Bhi, nullptr);
    gemm_mfma<<<gg, 256, 0, stream>>>(Ahi, Alo, Bhi, carry, b1 + l * DMODEL, 2, act);
  }

  finalize<<<EW, 256, 0, stream>>>(carry, out);
}

// Round 6
// 1852.859 us; speedup vs baseline: 6.3967x; 1.0546x over previous
//
#include <hip/hip_runtime.h>
#include <stdint.h>
#include <math.h>

// ============================================================================
// StackedEncoderModel, round 10.
//  - Diagnosis from rounds 2/4/5: GEMM time (~92-103us) is invariant to MFMA
//    count -> exposed VMEM latency at the vm-wait (loads waited <1 MFMA-burst
//    after issue), not pipe contention.
//  - Fix: 3-page LDS pipeline (72KB), staged 2.5 K-steps ahead. Per K-step:
//    vmcnt(12)+bar -> ds_read 12 frags -> 32 MFMA (compiler interleaves lgkm)
//    -> lgkm0+bar -> STAGE(tile t+3 into just-consumed page). A load gets two
//    full K-steps (~2500-3000cy) before its wait -> covers HBM-miss latency.
//  - fp16 2-term split retained (A=Ah+Al fp16, B=Bh fp16); verified round 9.
//  - XCD swizzle + fused GLU epilogues retained.
// ============================================================================

#define LAYERS 4
#define TT     4096
#define DMODEL 2048
#define DHID   1024
#define NCHUNK 64
#define CLEN   64   // TT / NCHUNK
#define KTILES 64   // 2048 / 32

typedef unsigned short ushort_t;
typedef __attribute__((ext_vector_type(8))) _Float16 half8;
typedef __attribute__((ext_vector_type(4))) float    f32x4;

// pack two floats as adjacent fp16 (RNE) into one dword
__device__ __forceinline__ unsigned pack2h(float a, float b) {
  _Float16 ha = (_Float16)a, hb = (_Float16)b;
  unsigned short ua = *(unsigned short*)&ha, ub = *(unsigned short*)&hb;
  return (unsigned)ua | ((unsigned)ub << 16);
}
__device__ __forceinline__ float lo_res(float v) {
  _Float16 h = (_Float16)v;
  return v - (float)h;
}

// ----------------------------------------------------------------------------
// convert_hilo: fp32 source (with B0/B1/NS/KS split addressing) -> fp16 hi
// (+ optional lo) in tiled layout: tile (mb,kb) = 128 rows x 32 k, stored
// [kg 0..3][m 0..127][j 0..7] fp16, 8KB per tile.
// ----------------------------------------------------------------------------
__global__ __launch_bounds__(256)
void convert_hilo(const float* __restrict__ B0, const float* __restrict__ B1,
                  int ldb, int NS, int KS,
                  ushort_t* __restrict__ Hi, ushort_t* __restrict__ Lo)
{
  __shared__ float tile[128][33];
  const int mb  = blockIdx.x;
  const int kb  = blockIdx.y;
  const int tid = threadIdx.x;
  const int r0  = tid >> 3;          // 0..31
  const int c0  = (tid & 7) * 4;     // 0..28
#pragma unroll
  for (int rep = 0; rep < 4; ++rep) {
    const int rr = rep * 32 + r0;
    const int n  = mb * 128 + rr;
    const int k  = kb * 32 + c0;
    const float* bp; long idx;
    if (n >= NS)      { bp = B1; idx = (long)(n - NS) * ldb + k; }
    else if (k >= KS) { bp = B1; idx = (long)n * ldb + (k - KS); }
    else              { bp = B0; idx = (long)n * ldb + k; }
#pragma unroll
    for (int u = 0; u < 4; ++u) tile[rr][c0 + u] = bp[idx + u];
  }
  __syncthreads();
#pragma unroll
  for (int rep = 0; rep < 2; ++rep) {
    const int id2 = rep * 256 + tid;
    const int kg  = id2 >> 7;        // 0..3
    const int m   = id2 & 127;
    const long off = ((long)mb * KTILES + kb) * 4096 + (kg * 128 + m) * 8;
    unsigned hw[4];
#pragma unroll
    for (int p = 0; p < 4; ++p)
      hw[p] = pack2h(tile[m][kg * 8 + p * 2], tile[m][kg * 8 + p * 2 + 1]);
    *(uint4*)&Hi[off] = make_uint4(hw[0], hw[1], hw[2], hw[3]);
    if (Lo) {
      unsigned lw[4];
#pragma unroll
      for (int p = 0; p < 4; ++p)
        lw[p] = pack2h(lo_res(tile[m][kg * 8 + p * 2]),
                       lo_res(tile[m][kg * 8 + p * 2 + 1]));
      *(uint4*)&Lo[off] = make_uint4(lw[0], lw[1], lw[2], lw[3]);
    }
  }
}

// ----------------------------------------------------------------------------
// bn_convert: BN-apply fused with fp16 hi/lo tiling. Writes act (xn fp32).
// ----------------------------------------------------------------------------
__global__ __launch_bounds__(256)
void bn_convert(const float* __restrict__ carry, const float* __restrict__ stats,
                const float* __restrict__ nw, const float* __restrict__ nb,
                float* __restrict__ act,
                ushort_t* __restrict__ Hi, ushort_t* __restrict__ Lo)
{
  __shared__ float tile[128][33];
  const int mb  = blockIdx.x;
  const int kb  = blockIdx.y;
  const int tid = threadIdx.x;
  const int r0  = tid >> 3;
  const int c0  = (tid & 7) * 4;
  float mean[4], rstd[4], w_[4], b_[4];
#pragma unroll
  for (int u = 0; u < 4; ++u) {
    const int j = kb * 32 + c0 + u;
    const float mu = stats[j] * (1.0f / TT);
    const float va = fmaxf(stats[DMODEL + j] * (1.0f / TT) - mu * mu, 0.0f);
    mean[u] = mu; rstd[u] = rsqrtf(va + 1e-5f);
    w_[u] = nw[j]; b_[u] = nb[j];
  }
#pragma unroll
  for (int rep = 0; rep < 4; ++rep) {
    const int rr  = rep * 32 + r0;
    const long base = (long)(mb * 128 + rr) * 2048 + kb * 32 + c0;
#pragma unroll
    for (int u = 0; u < 4; ++u) {
      const float v = (carry[base + u] - mean[u]) * rstd[u] * w_[u] + b_[u];
      tile[rr][c0 + u] = v;
      act[base + u] = v;
    }
  }
  __syncthreads();
#pragma unroll
  for (int rep = 0; rep < 2; ++rep) {
    const int id2 = rep * 256 + tid;
    const int kg  = id2 >> 7;
    const int m   = id2 & 127;
    const long off = ((long)mb * KTILES + kb) * 4096 + (kg * 128 + m) * 8;
    unsigned hw[4], lw[4];
#pragma unroll
    for (int p = 0; p < 4; ++p) {
      const float a = tile[m][kg * 8 + p * 2], b = tile[m][kg * 8 + p * 2 + 1];
      hw[p] = pack2h(a, b);
      lw[p] = pack2h(lo_res(a), lo_res(b));
    }
    *(uint4*)&Hi[off] = make_uint4(hw[0], hw[1], hw[2], hw[3]);
    *(uint4*)&Lo[off] = make_uint4(lw[0], lw[1], lw[2], lw[3]);
  }
}

// ----------------------------------------------------------------------------
// e1_convert: g = gelu(y + xn*d), emitted ONLY as tiled fp16 hi/lo.
// ----------------------------------------------------------------------------
__global__ __launch_bounds__(256)
void e1_convert(const float* __restrict__ y, const float* __restrict__ xn,
                const float* __restrict__ d,
                ushort_t* __restrict__ Hi, ushort_t* __restrict__ Lo)
{
  __shared__ float tile[128][33];
  const int mb  = blockIdx.x;
  const int kb  = blockIdx.y;
  const int tid = threadIdx.x;
  const int r0  = tid >> 3;
  const int c0  = (tid & 7) * 4;
  float dv[4];
#pragma unroll
  for (int u = 0; u < 4; ++u) dv[u] = d[kb * 32 + c0 + u];
#pragma unroll
  for (int rep = 0; rep < 4; ++rep) {
    const int rr  = rep * 32 + r0;
    const long base = (long)(mb * 128 + rr) * 2048 + kb * 32 + c0;
#pragma unroll
    for (int u = 0; u < 4; ++u) {
      const float v = y[base + u] + xn[base + u] * dv[u];
      tile[rr][c0 + u] = 0.5f * v * (1.0f + erff(v * 0.70710678118654752440f));
    }
  }
  __syncthreads();
#pragma unroll
  for (int rep = 0; rep < 2; ++rep) {
    const int id2 = rep * 256 + tid;
    const int kg  = id2 >> 7;
    const int m   = id2 & 127;
    const long off = ((long)mb * KTILES + kb) * 4096 + (kg * 128 + m) * 8;
    unsigned hw[4], lw[4];
#pragma unroll
    for (int p = 0; p < 4; ++p) {
      const float a = tile[m][kg * 8 + p * 2], b = tile[m][kg * 8 + p * 2 + 1];
      hw[p] = pack2h(a, b);
      lw[p] = pack2h(lo_res(a), lo_res(b));
    }
    *(uint4*)&Hi[off] = make_uint4(hw[0], hw[1], hw[2], hw[3]);
    *(uint4*)&Lo[off] = make_uint4(lw[0], lw[1], lw[2], lw[3]);
  }
}

// ----------------------------------------------------------------------------
// MFMA fp16 2-term GEMM, 3-page deep pipeline, XCD-swizzled. Grid 512 blocks.
// epi: 0 = C=acc+bias  1 = sigmoid(acc+bias)  2 = C += (acc+bias)*aux
// ----------------------------------------------------------------------------
#define GLDS(gp, lp) __builtin_amdgcn_global_load_lds( \
    (__attribute__((address_space(1))) void*)(void*)(gp), \
    (__attribute__((address_space(3))) void*)(lp), 16, 0, 0)

__global__ __launch_bounds__(256)
void gemm_mfma(const ushort_t* __restrict__ Ahi, const ushort_t* __restrict__ Alo,
               const ushort_t* __restrict__ Bhi,
               float* __restrict__ C, const float* __restrict__ bias,
               int epi, const float* __restrict__ aux)
{
  // 3 pages x 24KB: [Ah 8KB | Al 8KB | Bh 8KB] per page, 72KB total.
  __shared__ ushort_t S[3][12288];
  const int tid  = threadIdx.x;
  const int lane = tid & 63;
  const int wid  = tid >> 6;
  const int wm   = wid >> 1;
  const int wn   = wid & 1;

  // XCD swizzle: bid%8 = XCD; each XCD gets a contiguous 8x8 tile region.
  const int bid = blockIdx.y * gridDim.x + blockIdx.x;
  const int xcd = bid & 7, idx = bid >> 3;
  const int mb  = ((xcd & 3) << 3) | (idx & 7);   // 0..31
  const int nb  = ((xcd >> 2) << 3) | (idx >> 3); // 0..15

  f32x4 acc[4][4];
#pragma unroll
  for (int i = 0; i < 4; ++i)
#pragma unroll
    for (int j = 0; j < 4; ++j) acc[i][j] = (f32x4){0.f, 0.f, 0.f, 0.f};

  const ushort_t* ga_h = Ahi + (long)mb * KTILES * 4096 + tid * 8;
  const ushort_t* ga_l = Alo + (long)mb * KTILES * 4096 + tid * 8;
  const ushort_t* gb_h = Bhi + (long)nb * KTILES * 4096 + tid * 8;

  const int albase = ((lane >> 4) * 128 + wm * 64 + (lane & 15)) * 8;
  const int blbase = ((lane >> 4) * 128 + wn * 64 + (lane & 15)) * 8;

  half8 Ah[4], Al[4], Bh[4];

#define STAGE(P) \
  GLDS(ga_h,        &S[P][tid * 8]); \
  GLDS(ga_h + 2048, &S[P][2048 + tid * 8]); \
  GLDS(ga_l,        &S[P][4096 + tid * 8]); \
  GLDS(ga_l + 2048, &S[P][6144 + tid * 8]); \
  GLDS(gb_h,        &S[P][8192 + tid * 8]); \
  GLDS(gb_h + 2048, &S[P][10240 + tid * 8]); \
  ga_h += 4096; ga_l += 4096; gb_h += 4096;

#define RD_FRAGS(P) \
  _Pragma("unroll") \
  for (int m = 0; m < 4; ++m) { \
    Ah[m] = *(const half8*)&S[P][albase + m * 128]; \
    Al[m] = *(const half8*)&S[P][4096 + albase + m * 128]; \
  } \
  _Pragma("unroll") \
  for (int n = 0; n < 4; ++n) \
    Bh[n] = *(const half8*)&S[P][8192 + blbase + n * 128];

#define MFMA32 \
  __builtin_amdgcn_s_setprio(1); \
  _Pragma("unroll") \
  for (int m = 0; m < 4; ++m) \
    _Pragma("unroll") \
    for (int n = 0; n < 4; ++n) { \
      acc[m][n] = __builtin_amdgcn_mfma_f32_16x16x32_f16(Ah[m], Bh[n], acc[m][n], 0, 0, 0); \
      acc[m][n] = __builtin_amdgcn_mfma_f32_16x16x32_f16(Al[m], Bh[n], acc[m][n], 0, 0, 0); \
    } \
  __builtin_amdgcn_s_setprio(0);

#define WAIT_VM_BAR(n) asm volatile("s_waitcnt vmcnt(" #n ")" ::: "memory"); \
  __builtin_amdgcn_sched_barrier(0); __builtin_amdgcn_s_barrier();
#define LGKM0_BAR asm volatile("s_waitcnt lgkmcnt(0)" ::: "memory"); \
  __builtin_amdgcn_sched_barrier(0); __builtin_amdgcn_s_barrier();

// K-step with staging: tile t ready-wait, compute, then stage tile t+3 into
// the page just consumed (safe: all waves lgkm-drained at LGKM0_BAR).
#define KSTEP_S(P) \
  WAIT_VM_BAR(12) \
  RD_FRAGS(P) \
  MFMA32 \
  LGKM0_BAR \
  STAGE(P)

#define KSTEP_N(P, VMN) \
  WAIT_VM_BAR(VMN) \
  RD_FRAGS(P) \
  MFMA32

  // Prologue: stage tiles 0,1,2 (18 loads in flight).
  STAGE(0)
  STAGE(1)
  STAGE(2)

  // Main: t = 0..59 (20 x 3 pages), each stages tile t+3.
  for (int it = 0; it < 20; ++it) {
    KSTEP_S(0)
    KSTEP_S(1)
    KSTEP_S(2)
  }
  KSTEP_S(0)        // t=60, stages tile 63
  KSTEP_N(1, 12)    // t=61 (18 outstanding -> drain to 12: tile 61 landed)
  KSTEP_N(2, 6)     // t=62
  KSTEP_N(0, 0)     // t=63
#undef STAGE
#undef RD_FRAGS
#undef MFMA32
#undef WAIT_VM_BAR
#undef LGKM0_BAR
#undef KSTEP_S
#undef KSTEP_N

  // C/D layout (HW-verified): col = lane&15, row = (lane>>4)*4 + reg
  const int cn = lane & 15;
  const int cr = (lane >> 4) * 4;
#pragma unroll
  for (int m = 0; m < 4; ++m) {
    const long row = (long)mb * 128 + wm * 64 + m * 16 + cr;
#pragma unroll
    for (int n = 0; n < 4; ++n) {
      const int col = nb * 128 + wn * 64 + n * 16 + cn;
      const float bv = bias ? bias[col] : 0.0f;
      if (epi == 0) {
#pragma unroll
        for (int q = 0; q < 4; ++q)
          C[(row + q) * 2048 + col] = acc[m][n][q] + bv;
      } else if (epi == 1) {
#pragma unroll
        for (int q = 0; q < 4; ++q)
          C[(row + q) * 2048 + col] = 1.0f / (1.0f + expf(-(acc[m][n][q] + bv)));
      } else {
#pragma unroll
        for (int q = 0; q < 4; ++q) {
          const long idx2 = (row + q) * 2048 + col;
          C[idx2] += (acc[m][n][q] + bv) * aux[idx2];
        }
      }
    }
  }
}

// ---------------------------------------------------------------------------
// BatchNorm partial sums.
// ---------------------------------------------------------------------------
__global__ void bn_partial(const float* __restrict__ carry, float* __restrict__ stats)
{
  const int j  = blockIdx.x * 256 + threadIdx.x;
  const int r0 = blockIdx.y * 128;
  float s = 0.f, ss = 0.f;
  for (int r = 0; r < 128; ++r) {
    float v = carry[(long)(r0 + r) * DMODEL + j];
    s += v; ss += v * v;
  }
  atomicAdd(&stats[j], s);
  atomicAdd(&stats[DMODEL + j], ss);
}

// ---------------------------------------------------------------------------
// LRU blocked scan. Bu layout: fp32 [T][2048], cols 0:1024 re, 1024:2048 im.
// ---------------------------------------------------------------------------
__device__ __forceinline__ void get_lam(const float* nu_log, const float* th_log,
                                        int h, float& lre, float& lim)
{
  const float mag = expf(-expf(nu_log[h]));
  const float th  = expf(th_log[h]);
  lre = mag * cosf(th);
  lim = mag * sinf(th);
}

__global__ void scan1(float* __restrict__ bu,
                      const float* __restrict__ nu_log, const float* __restrict__ th_log,
                      const float* __restrict__ gl_log)
{
  const int gid = blockIdx.x * 256 + threadIdx.x;
  const int c = gid >> 10, h = gid & 1023;
  float lre, lim; get_lam(nu_log, th_log, h, lre, lim);
  const float gamma = expf(gl_log[h]);
  float hr = 0.f, hi = 0.f;
  for (int i = 0; i < CLEN; ++i) {
    const long t = (long)c * CLEN + i;
    const float br_ = bu[t * 2048 + h] * gamma;
    const float bi_ = bu[t * 2048 + 1024 + h] * gamma;
    const float nr = lre * hr - lim * hi + br_;
    const float ni = lre * hi + lim * hr + bi_;
    hr = nr; hi = ni;
    bu[t * 2048 + h] = hr;
    bu[t * 2048 + 1024 + h] = hi;
  }
}

__global__ void scan2(const float* __restrict__ loc,
                      float* __restrict__ ccre, float* __restrict__ ccim,
                      const float* __restrict__ nu_log, const float* __restrict__ th_log)
{
  const int h = blockIdx.x * 256 + threadIdx.x;  // 0..1023
  float lre, lim; get_lam(nu_log, th_log, h, lre, lim);
  float ar = lre, ai = lim;                       // lam^64 via 6 squarings
  for (int s = 0; s < 6; ++s) { float nr = ar * ar - ai * ai, ni = 2.f * ar * ai; ar = nr; ai = ni; }
  float er = 0.f, ei = 0.f;
  for (int c = 0; c < NCHUNK; ++c) {
    ccre[c * DHID + h] = er; ccim[c * DHID + h] = ei;
    const long t = (long)c * CLEN + (CLEN - 1);
    const float nr = ar * er - ai * ei + loc[t * 2048 + h];
    const float ni = ar * ei + ai * er + loc[t * 2048 + 1024 + h];
    er = nr; ei = ni;
  }
}

// scan3 runs IN PLACE on loc, leaving [h_re | -h_im] for the C-projection.
__global__ void scan3(float* __restrict__ loc,
                      const float* __restrict__ ccre, const float* __restrict__ ccim,
                      const float* __restrict__ nu_log, const float* __restrict__ th_log)
{
  const int gid = blockIdx.x * 256 + threadIdx.x;
  const int c = gid >> 10, h = gid & 1023;
  float lre, lim; get_lam(nu_log, th_log, h, lre, lim);
  const float cr_ = ccre[c * DHID + h], ci_ = ccim[c * DHID + h];
  float pr = lre, pi = lim;   // lam^(i+1)
  for (int i = 0; i < CLEN; ++i) {
    const long t = (long)c * CLEN + i;
    const float hre = loc[t * 2048 + h]        + pr * cr_ - pi * ci_;
    const float him = loc[t * 2048 + 1024 + h] + pr * ci_ + pi * cr_;
    const float npr = pr * lre - pi * lim, npi = pr * lim + pi * lre;
    pr = npr; pi = npi;
    loc[t * 2048 + h]        = hre;
    loc[t * 2048 + 1024 + h] = -him;
  }
}

// ---------------------------------------------------------------------------
__global__ void finalize(const float* __restrict__ carry, float* __restrict__ out)
{
  const long idx = (long)blockIdx.x * 256 + threadIdx.x;
  const float v = carry[idx];
  out[idx] = (v == v && fabsf(v) < 3.0e38f) ? v : 300000.0f;
}

__global__ void diagfill(float* __restrict__ out, float val)
{
  const long idx = (long)blockIdx.x * 256 + threadIdx.x;
  out[idx] = (idx == 0) ? val : 0.0f;
}

// ---------------------------------------------------------------------------
extern "C" void kernel_launch(void* const* d_in, const int* in_sizes, int n_in,
                              void* d_out, int out_size, void* d_ws, size_t ws_size,
                              hipStream_t stream)
{
  (void)out_size;
  const int EW = (TT * DMODEL) / 256;
  float* out = (float*)d_out;

  if (n_in != 17 || in_sizes[0] != TT * DMODEL) {
    diagfill<<<EW, 256, 0, stream>>>(out, (float)(1 << 18));
    return;
  }
  if (ws_size < 151600000ull) {
    diagfill<<<EW, 256, 0, stream>>>(out, (float)(1 << 12));
    return;
  }

  const float* x     = (const float*)d_in[0];
  const float* enc_w = (const float*)d_in[1];
  const float* enc_b = (const float*)d_in[2];
  const float* nu    = (const float*)d_in[3];
  const float* th    = (const float*)d_in[4];
  const float* gl    = (const float*)d_in[5];
  const float* Bre   = (const float*)d_in[6];
  const float* Bim   = (const float*)d_in[7];
  const float* Cre   = (const float*)d_in[8];
  const float* Cim   = (const float*)d_in[9];
  const float* Dd    = (const float*)d_in[10];
  const float* nw    = (const float*)d_in[11];
  const float* nb    = (const float*)d_in[12];
  const float* w1    = (const float*)d_in[13];
  const float* b1    = (const float*)d_in[14];
  const float* w2    = (const float*)d_in[15];
  const float* b2    = (const float*)d_in[16];

  char* ws = (char*)d_ws;
  float*    carry = (float*)(ws);                 // [T][DM] residual stream
  float*    act   = (float*)(ws + 33554432);      // xn -> sig(t2)
  float*    buf1  = (float*)(ws + 67108864);      // Bu -> ah -> y
  ushort_t* Ahi   = (ushort_t*)(ws + 100663296);  // tiled fp16 hi of A operand
  ushort_t* Alo   = (ushort_t*)(ws + 117440512);
  ushort_t* Bhi   = (ushort_t*)(ws + 134217728);  // tiled fp16 hi of B operand
  float*    ccre  = (float*)(ws + 150994944);
  float*    ccim  = (float*)(ws + 151257088);
  float*    stats = (float*)(ws + 151519232);

  const dim3 gcA(32, 64);   // 4096-row operand, 64 k-tiles
  const dim3 gcW(16, 64);   // 2048-row operand
  const dim3 gg(32, 16);    // GEMM: 512 blocks (swizzled in-kernel)
  const int BIG = 1 << 30;

  // encoder: carry = x @ enc_w^T + enc_b
  convert_hilo<<<gcA, 256, 0, stream>>>(x, x, 2048, BIG, BIG, Ahi, Alo);
  convert_hilo<<<gcW, 256, 0, stream>>>(enc_w, enc_w, 2048, BIG, BIG, Bhi, nullptr);
  gemm_mfma<<<gg, 256, 0, stream>>>(Ahi, Alo, Bhi, carry, enc_b, 0, nullptr);

  for (int l = 0; l < LAYERS; ++l) {
    const float* Brl = Bre + (size_t)l * DHID * DMODEL;
    const float* Bil = Bim + (size_t)l * DHID * DMODEL;
    const float* Crl = Cre + (size_t)l * DMODEL * DHID;
    const float* Cil = Cim + (size_t)l * DMODEL * DHID;
    const float* w1l = w1 + (size_t)l * DMODEL * DMODEL;
    const float* w2l = w2 + (size_t)l * DMODEL * DMODEL;

    // BatchNorm stats, then fused BN-apply + A-convert (act=xn + Ahi/Alo)
    hipMemsetAsync(stats, 0, 2 * DMODEL * sizeof(float), stream);
    bn_partial<<<dim3(DMODEL / 256, TT / 128), 256, 0, stream>>>(carry, stats);
    bn_convert<<<gcA, 256, 0, stream>>>(carry, stats, nw + l * DMODEL, nb + l * DMODEL,
                                        act, Ahi, Alo);

    // Bu = xn @ [B_re; B_im]^T  (row-split at 1024) -> buf1 [re|im]
    convert_hilo<<<gcW, 256, 0, stream>>>(Brl, Bil, 2048, 1024, BIG, Bhi, nullptr);
    gemm_mfma<<<gg, 256, 0, stream>>>(Ahi, Alo, Bhi, buf1, nullptr, 0, nullptr);

    // diagonal complex scan over T (scan3 in place: buf1 := [h_re | -h_im])
    scan1<<<256, 256, 0, stream>>>(buf1, nu + l * DHID, th + l * DHID, gl + l * DHID);
    scan2<<<4, 256, 0, stream>>>(buf1, ccre, ccim, nu + l * DHID, th + l * DHID);
    scan3<<<256, 256, 0, stream>>>(buf1, ccre, ccim, nu + l * DHID, th + l * DHID);

    // y = [h_re|-h_im] @ [C_re|C_im]^T (col-split at 1024, ldb=1024) -> buf1
    convert_hilo<<<gcA, 256, 0, stream>>>(buf1, buf1, 2048, BIG, BIG, Ahi, Alo);
    convert_hilo<<<gcW, 256, 0, stream>>>(Crl, Cil, 1024, BIG, 1024, Bhi, nullptr);
    gemm_mfma<<<gg, 256, 0, stream>>>(Ahi, Alo, Bhi, buf1, nullptr, 0, nullptr);

    // g = gelu(y + xn*d): fused elementwise + A-convert (hi/lo only)
    e1_convert<<<gcA, 256, 0, stream>>>(buf1, act, Dd + l * DMODEL, Ahi, Alo);

    // t2 first: act := sigmoid(g @ w2^T + b2)   (fused epilogue)
    convert_hilo<<<gcW, 256, 0, stream>>>(w2l, w2l, 2048, BIG, BIG, Bhi, nullptr);
    gemm_mfma<<<gg, 256, 0, stream>>>(Ahi, Alo, Bhi, act, b2 + l * DMODEL, 1, nullptr);

    // t1: carry += (g @ w1^T + b1) * act       (fused epilogue)
    convert_hilo<<<gcW, 256, 0, stream>>>(w1l, w1l, 2048, BIG, BIG, Bhi, nullptr);
    gemm_mfma<<<gg, 256, 0, stream>>>(Ahi, Alo, Bhi, carry, b1 + l * DMODEL, 2, act);
  }

  finalize<<<EW, 256, 0, stream>>>(carry, out);
}